// Round 9
// baseline (1023.679 us; speedup 1.0000x reference)
//
#include <hip/hip_runtime.h>
#include <math.h>

// Model constants: B=32, T=50000, P=100, D=512, H=16, L=6, C=256
// SCALES=[1,2,4], HS=5 heads/scale, KD=32, N=500 patches, FF=2048, EPS=1e-3.
//
// KEY INSIGHT (round 0, verified): first layernorm is over a size-1 axis ->
// output == ln_in_b[0] everywhere. h is batch-independent; network runs once
// on (500 x 512); final row broadcast x32.
//
// Round 6: bf16 MFMA GEMMs. R7/8: k-splits 999->839. R9: refused 1122.
// R10: branch-free staging 965. R11: sched_barrier+wo_combine 864.
// R12: splits+branch-free, no pinning: 803. R13: deeper splits: 797 —
// null result => per-dispatch FIXED cost dominates (launch+ramp+drain),
// not serial chunk chains.
// Round 14 (this round): cut 70 -> 58 dispatches via two staging-merges
// that add only batched L2-resident loads: (a) qkv_reduce folded into
// attn_split (4-partial sum + bias during Q-load / K,V staging; bias in
// LDS); (b) attn_combine folded into wo (Wcm preamble; A-staging combines
// <=4 oPart slices) WITHOUT sched_barrier this time — isolating the
// combine-fusion from the m141 pinning anti-pattern that confounded R11.

#define DD 512
#define NN 500
#define HSC 5
#define KDD 32
#define QKVN 160
#define QKV3 480
#define FF 2048
#define NL 6
#define NC 256
#define NB 32
#define LNEPS 1e-3f
#define BM 128
#define BN 64
#define KCHB 64

// aAll sub-buffer offsets (floats)
#define AOFF1 256000
#define AOFF2 384000
// total attn rows over scales (500+250+125)
#define RTOT 875
#define OSZ 140000      // RTOT*160
#define MLSZ 4384       // RTOT*5 rounded up
#define QSP 420000      // qkv partial slice stride (floats)

typedef __attribute__((ext_vector_type(8))) short bf16x8;
typedef __attribute__((ext_vector_type(4))) float f32x4;

__device__ __forceinline__ float gelu_exact(float x) {
    return 0.5f * x * (1.0f + erff(x * 0.70710678118654752f));
}

// pack two f32 -> two bf16 (RNE) in one instr
__device__ __forceinline__ unsigned int pkbf(float a, float b) {
    unsigned int r;
    asm("v_cvt_pk_bf16_f32 %0, %1, %2" : "=v"(r) : "v"(a), "v"(b));
    return r;
}

__device__ __forceinline__ float4 f4add(float4 a, float4 b) {
    return make_float4(a.x + b.x, a.y + b.y, a.z + b.z, a.w + b.w);
}

// ======================= MFMA GEMM core =======================
// Tile: BM=128 x BN=64, 256 threads = 4 waves (2x2), K-chunk 64.
// A fp32 [M][K] (lda), POOL row-pooling or 3-scale GATHER (compile-time);
// B fp32 [K][N]: caller resolves per-thread column -> Bcol (always valid).
// ALL loads unconditional/branch-free: rows clamped to M-1 (dup rows never
// stored); TAIL>0: addresses clamped to klim, tail values masked via
// cndmask (A side only; B garbage x A-zero = 0).
// LDS row pitch 128B, swizzle byte ^= ((row&7)<<4) -> conflict-free b128.

template<int POOL, int GATHER, int TAIL>
__device__ __forceinline__ void mstage(
        const float* __restrict__ A, int lda,
        const float* __restrict__ Bcol, int ldb,
        int M, int bm, int k0, int klim,
        int ar4, int akq, int bkq,
        float4 (&aR)[2][4], float4 (&bR)[4]) {
    #pragma unroll
    for (int p = 0; p < 2; ++p) {
        int row = min(bm + ar4 + p * 64, M - 1);
        const float* ap;
        if (!GATHER) {
            ap = A + (size_t)row * POOL * lda;
        } else {
            int si = k0 >> 9;
            ap = A + (si == 0 ? 0 : (si == 1 ? AOFF1 : AOFF2))
               + (size_t)(row >> si) * DD - (size_t)(k0 & ~(DD - 1));
        }
        #pragma unroll
        for (int i = 0; i < 4; ++i) {
            int kk = akq + i * 4;
            int kg = TAIL ? min(k0 + kk, klim - 4) : (k0 + kk);
            float4 v = *(const float4*)(ap + kg);
            #pragma unroll
            for (int t = 1; t < POOL; ++t) {
                float4 u = *(const float4*)(ap + kg + (size_t)t * lda);
                v.x += u.x; v.y += u.y; v.z += u.z; v.w += u.w;
            }
            if (POOL > 1) {
                const float ip = 1.0f / (float)POOL;
                v.x *= ip; v.y *= ip; v.z *= ip; v.w *= ip;
            }
            if (TAIL) {
                bool ok = (k0 + kk) < klim;       // cndmask, no branch
                v.x = ok ? v.x : 0.f; v.y = ok ? v.y : 0.f;
                v.z = ok ? v.z : 0.f; v.w = ok ? v.w : 0.f;
            }
            aR[p][i] = v;
        }
    }
    #pragma unroll
    for (int i = 0; i < 4; ++i) {
        int kr = TAIL ? min(k0 + bkq + i, klim - 1) : (k0 + bkq + i);
        bR[i] = *(const float4*)(Bcol + (size_t)kr * ldb);
    }
}

template<int POOL, int GATHER, int TAIL>
__device__ __forceinline__ void mfma_core(
        const float* __restrict__ A, int lda,
        const float* __restrict__ Bcol, int ldb,
        int M, int bm, int ks, int nch, int klim, f32x4 (&acc)[4][2]) {
    __shared__ __align__(16) unsigned short As[128 * 64];   // 16 KB
    __shared__ __align__(16) unsigned short Bs[64 * 64];    // 8 KB
    const int tid = threadIdx.x;
    const int ar4 = tid >> 2, akq = (tid & 3) * 16;   // A: 2 rows, 16 k each
    const int bkq = (tid >> 4) * 4, bn4 = tid & 15;   // B: 4 k-rows, col quad
    const int lane = tid & 63, wid = tid >> 6;
    const int wm = wid >> 1, wn = wid & 1;

    float4 aR[2][4], bR[4];
    mstage<POOL, GATHER, TAIL>(A, lda, Bcol, ldb, M, bm, ks, klim,
                               ar4, akq, bkq, aR, bR);

    for (int c = 0; c < nch; ++c) {
        __syncthreads();
        // ---- regs -> LDS (cvt to bf16, swizzled) ----
        #pragma unroll
        for (int p = 0; p < 2; ++p) {
            int r = ar4 + p * 64;
            int swz = (r & 7) << 4;
            char* base = (char*)As + r * 128;
            #pragma unroll
            for (int i = 0; i < 4; ++i) {
                int cb = (akq + i * 4) * 2;
                *(uint2*)(base + (cb ^ swz)) = make_uint2(
                    pkbf(aR[p][i].x, aR[p][i].y), pkbf(aR[p][i].z, aR[p][i].w));
            }
        }
        {
            const float* b0 = (const float*)&bR[0];
            const float* b1 = (const float*)&bR[1];
            const float* b2 = (const float*)&bR[2];
            const float* b3 = (const float*)&bR[3];
            #pragma unroll
            for (int j = 0; j < 4; ++j) {
                int nrow = bn4 * 4 + j;
                char* base = (char*)Bs + nrow * 128;
                *(uint2*)(base + ((bkq * 2) ^ ((nrow & 7) << 4))) = make_uint2(
                    pkbf(b0[j], b1[j]), pkbf(b2[j], b3[j]));
            }
        }
        __syncthreads();
        if (c + 1 < nch)
            mstage<POOL, GATHER, TAIL>(A, lda, Bcol, ldb, M, bm,
                                       ks + (c + 1) * KCHB, klim,
                                       ar4, akq, bkq, aR, bR);
        // ---- compute: 2 k-steps of 32, 8 MFMA each per wave ----
        #pragma unroll
        for (int half = 0; half < 2; ++half) {
            const int kb = (half * 32 + (lane >> 4) * 8) * 2;
            bf16x8 af[4], bf[2];
            #pragma unroll
            for (int m = 0; m < 4; ++m) {
                int r = wm * 64 + m * 16 + (lane & 15);
                af[m] = *(const bf16x8*)((const char*)As + r * 128 + (kb ^ ((r & 7) << 4)));
            }
            #pragma unroll
            for (int n = 0; n < 2; ++n) {
                int r = wn * 32 + n * 16 + (lane & 15);
                bf[n] = *(const bf16x8*)((const char*)Bs + r * 128 + (kb ^ ((r & 7) << 4)));
            }
            #pragma unroll
            for (int m = 0; m < 4; ++m)
                #pragma unroll
                for (int n = 0; n < 2; ++n)
                    acc[m][n] = __builtin_amdgcn_mfma_f32_16x16x32_bf16(
                        af[m], bf[n], acc[m][n], 0, 0, 0);
        }
    }
}

#define MACC_INIT(acc) { _Pragma("unroll") for (int m_ = 0; m_ < 4; ++m_) \
    _Pragma("unroll") for (int n_ = 0; n_ < 2; ++n_) \
    _Pragma("unroll") for (int j_ = 0; j_ < 4; ++j_) acc[m_][n_][j_] = 0.f; }

// ======================= setup =======================
__global__ void colsum_kernel(const float* __restrict__ pw, float* __restrict__ csum) {
    int d = blockIdx.x * blockDim.x + threadIdx.x;
    if (d < DD) {
        float s = 0.f;
        for (int p = 0; p < 100; ++p) s += pw[p * DD + d];
        csum[d] = s;
    }
}

__global__ void init_h(const float* __restrict__ csum, const float* __restrict__ pb,
                       const float* __restrict__ pos, const float* __restrict__ lnb,
                       float* __restrict__ h) {
    int idx = blockIdx.x * 256 + threadIdx.x;
    if (idx >= NN * DD) return;
    int d = idx & (DD - 1);
    h[idx] = lnb[0] * csum[d] + pb[d] + pos[idx];
}

// ======================= QKV partial (all scales, k-split S=4) =============
// grid (8, 4, 12): x = 64-col tile over 480 (q|k|v), y = 128-row tile,
// z = scale*4 + ps (k quarter of 128). Partials consumed (w/ bias) by attn.
__global__ __launch_bounds__(256, 2) void qkv_part(
        const float* __restrict__ h,
        const float* __restrict__ Wq, const float* __restrict__ Wk,
        const float* __restrict__ Wv,
        float* __restrict__ part, int l) {
    int scale = blockIdx.z >> 2, ps = blockIdx.z & 3;
    int n = NN >> scale;
    int bm = blockIdx.y * BM;
    if (bm >= n) return;
    int bn = blockIdx.x * BN;
    size_t w = (size_t)(l * 3 + scale);
    int tid = threadIdx.x;
    int col = min(bn + (tid & 15) * 4, QKV3 - 4);
    int which = (col >= 320) ? 2 : ((col >= 160) ? 1 : 0);
    const float* Wsel = (which == 0) ? Wq : ((which == 1) ? Wk : Wv);
    const float* Bcol = Wsel + w * DD * QKVN + (col - which * QKVN);
    float* outb = part + (size_t)ps * QSP
                + (scale == 0 ? 0 : (scale == 1 ? 240000 : 360000));

    f32x4 acc[4][2];
    MACC_INIT(acc);
    if (scale == 0)
        mfma_core<1, 0, 0>(h, DD, Bcol, QKVN, n, bm, ps * 128, 2, DD, acc);
    else if (scale == 1)
        mfma_core<2, 0, 0>(h, DD, Bcol, QKVN, n, bm, ps * 128, 2, DD, acc);
    else
        mfma_core<4, 0, 0>(h, DD, Bcol, QKVN, n, bm, ps * 128, 2, DD, acc);

    int lane = tid & 63, wid = tid >> 6, wm = wid >> 1, wn = wid & 1;
    #pragma unroll
    for (int q = 0; q < 2; ++q) {
        int cb = bn + wn * 32 + q * 16;
        if (cb >= QKV3) continue;
        int c2 = cb + (lane & 15);
        #pragma unroll
        for (int m = 0; m < 4; ++m) {
            int r0 = bm + wm * 64 + m * 16 + ((lane >> 4) << 2);
            #pragma unroll
            for (int j = 0; j < 4; ++j) {
                int r = r0 + j;
                if (r < n) outb[(size_t)r * QKV3 + c2] = acc[m][q][j];
            }
        }
    }
}

// ======================= attention: key-split flash + qkv combine ==========
// Reads 4 qkv partials + bias directly (qkv_reduce eliminated).
__global__ __launch_bounds__(256, 2) void attn_split(
        const float* __restrict__ qkvP,
        const float* __restrict__ bq, const float* __restrict__ bk,
        const float* __restrict__ bv,
        float* __restrict__ oPart,
        float* __restrict__ mPart, float* __restrict__ lPart, int l) {
    int z = blockIdx.z;
    int scale, sp;
    if (z < 4)      { scale = 0; sp = z; }
    else if (z < 6) { scale = 1; sp = z - 4; }
    else            { scale = 2; sp = 0; }
    int n = NN >> scale;
    int qt = blockIdx.x;
    if (qt * 64 >= n) return;
    int hh = blockIdx.y;
    int ks = sp * 128;
    int ke = min(n, ks + 128);
    const float* qkv = qkvP + (scale == 0 ? 0 : (scale == 1 ? 240000 : 360000));
    int rowb = (scale == 0 ? 0 : (scale == 1 ? 500 : 750));
    size_t wb = (size_t)(l * 3 + scale) * QKVN + hh * KDD;

    int tid = threadIdx.x;
    int kg = tid & 7, qq = tid >> 3;
    int q0 = qt * 64 + qq, q1 = q0 + 32;
    bool ok0 = q0 < n, ok1 = q1 < n;

    __shared__ float bQs[32], bKs[32], bVs[32];
    if (tid < 32) bQs[tid] = bq[wb + tid];
    else if (tid < 64) bKs[tid - 32] = bk[wb + tid - 32];
    else if (tid < 96) bVs[tid - 64] = bv[wb + tid - 64];
    __syncthreads();

    float qa[32], qb[32];
    {
        const float* p0 = qkv + (size_t)(ok0 ? q0 : 0) * QKV3 + hh * KDD;
        const float* p1 = qkv + (size_t)(ok1 ? q1 : 0) * QKV3 + hh * KDD;
        #pragma unroll
        for (int c4 = 0; c4 < 8; ++c4) {
            float4 b4 = *(const float4*)&bQs[c4 * 4];
            float4 v0 = f4add(f4add(*(const float4*)(p0 + c4 * 4),
                                    *(const float4*)(p0 + QSP + c4 * 4)),
                              f4add(*(const float4*)(p0 + 2 * QSP + c4 * 4),
                                    *(const float4*)(p0 + 3 * QSP + c4 * 4)));
            float4 v1 = f4add(f4add(*(const float4*)(p1 + c4 * 4),
                                    *(const float4*)(p1 + QSP + c4 * 4)),
                              f4add(*(const float4*)(p1 + 2 * QSP + c4 * 4),
                                    *(const float4*)(p1 + 3 * QSP + c4 * 4)));
            v0 = f4add(v0, b4); v1 = f4add(v1, b4);
            qa[c4 * 4] = v0.x; qa[c4 * 4 + 1] = v0.y; qa[c4 * 4 + 2] = v0.z; qa[c4 * 4 + 3] = v0.w;
            qb[c4 * 4] = v1.x; qb[c4 * 4 + 1] = v1.y; qb[c4 * 4 + 2] = v1.z; qb[c4 * 4 + 3] = v1.w;
        }
    }

    __shared__ float Ks[64][36];
    __shared__ float Vs[64][36];
    float o0[32], o1[32];
    #pragma unroll
    for (int c = 0; c < 32; ++c) { o0[c] = 0.f; o1[c] = 0.f; }
    float m0 = -1e30f, m1 = -1e30f, l0 = 0.f, l1 = 0.f;

    int srow = tid >> 2, scol = tid & 3;

    for (int kc = ks; kc < ke; kc += 64) {
        __syncthreads();
        int krow = kc + srow;
        bool ok = krow < ke;
        const float* kp = qkv + (size_t)(ok ? krow : 0) * QKV3 + QKVN + hh * KDD;
        #pragma unroll
        for (int half = 0; half < 2; ++half) {
            int cc = (half * 4 + scol) * 4;
            float4 kv = f4add(f4add(*(const float4*)(kp + cc),
                                    *(const float4*)(kp + QSP + cc)),
                              f4add(*(const float4*)(kp + 2 * QSP + cc),
                                    *(const float4*)(kp + 3 * QSP + cc)));
            float4 vv = f4add(f4add(*(const float4*)(kp + QKVN + cc),
                                    *(const float4*)(kp + QKVN + QSP + cc)),
                              f4add(*(const float4*)(kp + QKVN + 2 * QSP + cc),
                                    *(const float4*)(kp + QKVN + 3 * QSP + cc)));
            kv = f4add(kv, *(const float4*)&bKs[cc]);
            vv = f4add(vv, *(const float4*)&bVs[cc]);
            if (!ok) { kv = make_float4(0.f, 0.f, 0.f, 0.f);
                       vv = make_float4(0.f, 0.f, 0.f, 0.f); }
            Ks[srow][cc] = kv.x; Ks[srow][cc + 1] = kv.y; Ks[srow][cc + 2] = kv.z; Ks[srow][cc + 3] = kv.w;
            Vs[srow][cc] = vv.x; Vs[srow][cc + 1] = vv.y; Vs[srow][cc + 2] = vv.z; Vs[srow][cc + 3] = vv.w;
        }
        __syncthreads();

        float p0[8], p1[8];
        float cm = -1e30f;
        #pragma unroll
        for (int jj = 0; jj < 8; ++jj) {
            int j = jj * 8 + kg;
            float s0 = 0.f, s1 = 0.f;
            #pragma unroll
            for (int c4 = 0; c4 < 8; ++c4) {
                float4 kv = *(const float4*)&Ks[j][c4 * 4];
                s0 += qa[c4 * 4] * kv.x + qa[c4 * 4 + 1] * kv.y
                    + qa[c4 * 4 + 2] * kv.z + qa[c4 * 4 + 3] * kv.w;
                s1 += qb[c4 * 4] * kv.x + qb[c4 * 4 + 1] * kv.y
                    + qb[c4 * 4 + 2] * kv.z + qb[c4 * 4 + 3] * kv.w;
            }
            s0 *= 0.17677669529663687f;
            s1 *= 0.17677669529663687f;
            if (kc + j >= ke) { s0 = -1e30f; s1 = -1e30f; }
            p0[jj] = s0; p1[jj] = s1;
            cm = fmaxf(cm, fmaxf(s0, s1));
        }
        cm = fmaxf(cm, __shfl_xor(cm, 1));
        cm = fmaxf(cm, __shfl_xor(cm, 2));
        cm = fmaxf(cm, __shfl_xor(cm, 4));

        float mn0 = fmaxf(m0, cm), mn1 = fmaxf(m1, cm);
        float al0 = expf(m0 - mn0), al1 = expf(m1 - mn1);
        m0 = mn0; m1 = mn1;
        float ls0 = 0.f, ls1 = 0.f;
        #pragma unroll
        for (int jj = 0; jj < 8; ++jj) {
            p0[jj] = expf(p0[jj] - mn0); ls0 += p0[jj];
            p1[jj] = expf(p1[jj] - mn1); ls1 += p1[jj];
        }
        l0 = l0 * al0 + ls0;
        l1 = l1 * al1 + ls1;
        #pragma unroll
        for (int c = 0; c < 32; ++c) { o0[c] *= al0; o1[c] *= al1; }
        #pragma unroll
        for (int jj = 0; jj < 8; ++jj) {
            int j = jj * 8 + kg;
            float w0 = p0[jj], w1 = p1[jj];
            #pragma unroll
            for (int c4 = 0; c4 < 8; ++c4) {
                float4 vv = *(const float4*)&Vs[j][c4 * 4];
                o0[c4 * 4]     += w0 * vv.x; o0[c4 * 4 + 1] += w0 * vv.y;
                o0[c4 * 4 + 2] += w0 * vv.z; o0[c4 * 4 + 3] += w0 * vv.w;
                o1[c4 * 4]     += w1 * vv.x; o1[c4 * 4 + 1] += w1 * vv.y;
                o1[c4 * 4 + 2] += w1 * vv.z; o1[c4 * 4 + 3] += w1 * vv.w;
            }
        }
    }
    #pragma unroll
    for (int st = 1; st < 8; st <<= 1) {
        l0 += __shfl_xor(l0, st);
        l1 += __shfl_xor(l1, st);
        #pragma unroll
        for (int c = 0; c < 32; ++c) {
            o0[c] += __shfl_xor(o0[c], st);
            o1[c] += __shfl_xor(o1[c], st);
        }
    }
    if (kg == 0) {
        float* ob = oPart + (size_t)sp * OSZ;
        if (ok0) {
            int r = rowb + q0;
            float* op = ob + (size_t)r * QKVN + hh * KDD;
            #pragma unroll
            for (int c4 = 0; c4 < 8; ++c4) {
                float4 v; v.x = o0[c4*4]; v.y = o0[c4*4+1]; v.z = o0[c4*4+2]; v.w = o0[c4*4+3];
                *(float4*)(op + c4 * 4) = v;
            }
            mPart[sp * MLSZ + r * HSC + hh] = m0;
            lPart[sp * MLSZ + r * HSC + hh] = l0;
        }
        if (ok1) {
            int r = rowb + q1;
            float* op = ob + (size_t)r * QKVN + hh * KDD;
            #pragma unroll
            for (int c4 = 0; c4 < 8; ++c4) {
                float4 v; v.x = o1[c4*4]; v.y = o1[c4*4+1]; v.z = o1[c4*4+2]; v.w = o1[c4*4+3];
                *(float4*)(op + c4 * 4) = v;
            }
            mPart[sp * MLSZ + r * HSC + hh] = m1;
            lPart[sp * MLSZ + r * HSC + hh] = l1;
        }
    }
}

// ======================= Wo + combine fused (all scales) ===================
// Combine weights w_s=exp(m_s-M)/L in LDS; A-staging combines <=4 oPart
// slices on the fly. Branch-free; NO sched_barrier (m141).
__global__ __launch_bounds__(256, 2) void wo_combine(
        const float* __restrict__ oPart, const float* __restrict__ mPart,
        const float* __restrict__ lPart, const float* __restrict__ Wo,
        const float* __restrict__ bo, float* __restrict__ aAll, int l) {
    int z = blockIdx.z;
    int n = NN >> z;
    int ns = 4 >> z;
    int bm = blockIdx.y * BM;
    if (bm >= n) return;
    int bn = blockIdx.x * BN;
    int rowb = (z == 0 ? 0 : (z == 1 ? 500 : 750));
    size_t w = (size_t)(l * 3 + z);
    int tid = threadIdx.x;
    const float* Bcol = Wo + w * QKVN * DD + bn + (tid & 15) * 4;
    float* C = aAll + (z == 0 ? 0 : (z == 1 ? AOFF1 : AOFF2));

    __shared__ __align__(16) unsigned short As[128 * 64];   // 16 KB
    __shared__ __align__(16) unsigned short Bs[64 * 64];    // 8 KB
    __shared__ __align__(16) float Wcm[128][24];            // 12 KB

    for (int it = tid; it < 128 * HSC; it += 256) {
        int lrow = it / HSC, hh = it - lrow * HSC;
        float w4[4] = {0.f, 0.f, 0.f, 0.f};
        int row = bm + lrow;
        if (row < n) {
            int gr = rowb + row;
            float M = -1e30f;
            for (int s = 0; s < ns; ++s)
                M = fmaxf(M, mPart[s * MLSZ + gr * HSC + hh]);
            float L = 0.f;
            for (int s = 0; s < ns; ++s) {
                float e = expf(mPart[s * MLSZ + gr * HSC + hh] - M);
                w4[s] = e;
                L += e * lPart[s * MLSZ + gr * HSC + hh];
            }
            float inv = 1.f / L;
            for (int s = 0; s < ns; ++s) w4[s] *= inv;
        }
        Wcm[lrow][hh * 4 + 0] = w4[0];
        Wcm[lrow][hh * 4 + 1] = w4[1];
        Wcm[lrow][hh * 4 + 2] = w4[2];
        Wcm[lrow][hh * 4 + 3] = w4[3];
    }
    __syncthreads();

    const int ar4 = tid >> 2, akq = (tid & 3) * 16;
    const int bkq = (tid >> 4) * 4, bn4 = tid & 15;
    const int lane = tid & 63, wid = tid >> 6;
    const int wm = wid >> 1, wn = wid & 1;

    f32x4 acc[4][2];
    MACC_INIT(acc);
    float4 aR[2][4], bR[4];

    auto stage = [&](int k0) {
        int krem = QKVN - k0;
        #pragma unroll
        for (int p = 0; p < 2; ++p) {
            int row = min(bm + ar4 + p * 64, n - 1);
            int lrowc = row - bm;
            #pragma unroll
            for (int i = 0; i < 4; ++i) {
                int kk = akq + i * 4;
                int k = min(k0 + kk, QKVN - 4);
                int hh = min(k >> 5, 4);
                float4 w4 = *(const float4*)&Wcm[lrowc][hh * 4];
                size_t off = (size_t)(rowb + row) * QKVN + k;
                float4 a0 = *(const float4*)(oPart + off);
                float4 v;
                v.x = w4.x * a0.x; v.y = w4.x * a0.y;
                v.z = w4.x * a0.z; v.w = w4.x * a0.w;
                if (ns > 1) {
                    float4 a1 = *(const float4*)(oPart + OSZ + off);
                    v.x += w4.y * a1.x; v.y += w4.y * a1.y;
                    v.z += w4.y * a1.z; v.w += w4.y * a1.w;
                }
                if (ns > 2) {
                    float4 a2 = *(const float4*)(oPart + 2 * OSZ + off);
                    float4 a3 = *(const float4*)(oPart + 3 * OSZ + off);
                    v.x += w4.z * a2.x + w4.w * a3.x;
                    v.y += w4.z * a2.y + w4.w * a3.y;
                    v.z += w4.z * a2.z + w4.w * a3.z;
                    v.w += w4.z * a2.w + w4.w * a3.w;
                }
                bool kv_ = kk < krem;
                v.x = kv_ ? v.x : 0.f; v.y = kv_ ? v.y : 0.f;
                v.z = kv_ ? v.z : 0.f; v.w = kv_ ? v.w : 0.f;
                aR[p][i] = v;
            }
        }
        #pragma unroll
        for (int i = 0; i < 4; ++i) {
            int krow = min(k0 + bkq + i, QKVN - 1);
            bR[i] = *(const float4*)(Bcol + (size_t)krow * DD);
        }
    };

    const int nch = 3;   // K=160: chunks of 64,64,32
    stage(0);
    for (int c = 0; c < nch; ++c) {
        __syncthreads();
        #pragma unroll
        for (int p = 0; p < 2; ++p) {
            int r = ar4 + p * 64;
            int swz = (r & 7) << 4;
            char* base = (char*)As + r * 128;
            #pragma unroll
            for (int i = 0; i < 4; ++i) {
                int cb = (akq + i * 4) * 2;
                *(uint2*)(base + (cb ^ swz)) = make_uint2(
                    pkbf(aR[p][i].x, aR[p][i].y), pkbf(aR[p][i].z, aR[p][i].w));
            }
        }
        {
            const float* b0 = (const float*)&bR[0];
            const float* b1 = (const float*)&bR[1];
            const float* b2 = (const float*)&bR[2];
            const float* b3 = (const float*)&bR[3];
            #pragma unroll
            for (int j = 0; j < 4; ++j) {
                int nrow = bn4 * 4 + j;
                char* base = (char*)Bs + nrow * 128;
                *(uint2*)(base + ((bkq * 2) ^ ((nrow & 7) << 4))) = make_uint2(
                    pkbf(b0[j], b1[j]), pkbf(b2[j], b3[j]));
            }
        }
        __syncthreads();
        if (c + 1 < nch) stage((c + 1) * KCHB);
        #pragma unroll
        for (int half = 0; half < 2; ++half) {
            const int kb = (half * 32 + (lane >> 4) * 8) * 2;
            bf16x8 af[4], bf[2];
            #pragma unroll
            for (int m = 0; m < 4; ++m) {
                int r = wm * 64 + m * 16 + (lane & 15);
                af[m] = *(const bf16x8*)((const char*)As + r * 128 + (kb ^ ((r & 7) << 4)));
            }
            #pragma unroll
            for (int n2 = 0; n2 < 2; ++n2) {
                int r = wn * 32 + n2 * 16 + (lane & 15);
                bf[n2] = *(const bf16x8*)((const char*)Bs + r * 128 + (kb ^ ((r & 7) << 4)));
            }
            #pragma unroll
            for (int m = 0; m < 4; ++m)
                #pragma unroll
                for (int n2 = 0; n2 < 2; ++n2)
                    acc[m][n2] = __builtin_amdgcn_mfma_f32_16x16x32_bf16(
                        af[m], bf[n2], acc[m][n2], 0, 0, 0);
        }
    }

    const float* bias = bo + w * DD;
    #pragma unroll
    for (int q = 0; q < 2; ++q) {
        int c2 = bn + wn * 32 + q * 16 + (lane & 15);
        float bv_ = bias[c2];
        #pragma unroll
        for (int m = 0; m < 4; ++m) {
            int r0 = bm + wm * 64 + m * 16 + ((lane >> 4) << 2);
            #pragma unroll
            for (int j = 0; j < 4; ++j) {
                int r = r0 + j;
                if (r < n) C[(size_t)r * DD + c2] = acc[m][q][j] + bv_;
            }
        }
    }
}

// ======================= comb partial (gather-A, k-split S=12) =============
__global__ __launch_bounds__(256, 2) void comb_part(
        const float* __restrict__ aAll, const float* __restrict__ Wc,
        float* __restrict__ part) {
    int zz = blockIdx.z;
    int bm = blockIdx.y * BM, bn = blockIdx.x * BN;
    int tid = threadIdx.x;
    const float* Bcol = Wc + bn + (tid & 15) * 4;
    f32x4 acc[4][2];
    MACC_INIT(acc);
    mfma_core<1, 1, 0>(aAll, DD, Bcol, DD, NN, bm, zz * 128, 2, 1536, acc);

    float* pz = part + (size_t)zz * NN * DD;
    int lane = tid & 63, wid = tid >> 6, wm = wid >> 1, wn = wid & 1;
    #pragma unroll
    for (int q = 0; q < 2; ++q) {
        int c2 = bn + wn * 32 + q * 16 + (lane & 15);
        #pragma unroll
        for (int m = 0; m < 4; ++m) {
            int r0 = bm + wm * 64 + m * 16 + ((lane >> 4) << 2);
            #pragma unroll
            for (int j = 0; j < 4; ++j) {
                int r = r0 + j;
                if (r < NN) pz[(size_t)r * DD + c2] = acc[m][q][j];
            }
        }
    }
}

// ======================= W1 partial (k-split S=4) ==========================
__global__ __launch_bounds__(256, 2) void w1_part(
        const float* __restrict__ h, const float* __restrict__ W1,
        float* __restrict__ part) {
    int sp = blockIdx.z;
    int bm = blockIdx.y * BM, bn = blockIdx.x * BN;
    int tid = threadIdx.x;
    const float* Bcol = W1 + bn + (tid & 15) * 4;
    f32x4 acc[4][2];
    MACC_INIT(acc);
    mfma_core<1, 0, 0>(h, DD, Bcol, FF, NN, bm, sp * 128, 2, DD, acc);

    float* pz = part + (size_t)sp * NN * FF;
    int lane = tid & 63, wid = tid >> 6, wm = wid >> 1, wn = wid & 1;
    #pragma unroll
    for (int q = 0; q < 2; ++q) {
        int c2 = bn + wn * 32 + q * 16 + (lane & 15);
        #pragma unroll
        for (int m = 0; m < 4; ++m) {
            int r0 = bm + wm * 64 + m * 16 + ((lane >> 4) << 2);
            #pragma unroll
            for (int j = 0; j < 4; ++j) {
                int r = r0 + j;
                if (r < NN) pz[(size_t)r * FF + c2] = acc[m][q][j];
            }
        }
    }
}

__global__ void w1_reduce(const float* __restrict__ part,
                          const float* __restrict__ b1, float* __restrict__ f) {
    int idx = blockIdx.x * 256 + threadIdx.x;
    if (idx >= NN * FF) return;
    float v = part[idx] + part[NN * FF + idx]
            + part[2 * NN * FF + idx] + part[3 * NN * FF + idx];
    f[idx] = gelu_exact(v + b1[idx & (FF - 1)]);
}

// ======================= W2 partial (k-split S=16) =========================
__global__ __launch_bounds__(256, 2) void w2_part(
        const float* __restrict__ f, const float* __restrict__ W2,
        float* __restrict__ part) {
    int sp = blockIdx.z;
    int bm = blockIdx.y * BM, bn = blockIdx.x * BN;
    int tid = threadIdx.x;
    const float* Bcol = W2 + bn + (tid & 15) * 4;
    f32x4 acc[4][2];
    MACC_INIT(acc);
    mfma_core<1, 0, 0>(f, FF, Bcol, DD, NN, bm, sp * 128, 2, FF, acc);

    float* pz = part + (size_t)sp * NN * DD;
    int lane = tid & 63, wid = tid >> 6, wm = wid >> 1, wn = wid & 1;
    #pragma unroll
    for (int q = 0; q < 2; ++q) {
        int c2 = bn + wn * 32 + q * 16 + (lane & 15);
        #pragma unroll
        for (int m = 0; m < 4; ++m) {
            int r0 = bm + wm * 64 + m * 16 + ((lane >> 4) << 2);
            #pragma unroll
            for (int j = 0; j < 4; ++j) {
                int r = r0 + j;
                if (r < NN) pz[(size_t)r * DD + c2] = acc[m][q][j];
            }
        }
    }
}

// ======================= fused reduce + bias + residual + LN ===============
__global__ void reduce_add_ln(const float* __restrict__ part, int S,
                              const float* __restrict__ bias,
                              float* __restrict__ h,
                              const float* __restrict__ gw,
                              const float* __restrict__ bw) {
    int row = blockIdx.x, t = threadIdx.x;
    size_t idx = (size_t)row * DD + t;
    float x = h[idx] + bias[t];
    for (int s = 0; s < S; ++s) x += part[(size_t)s * NN * DD + idx];
    int lane = t & 63, wv = t >> 6;
    __shared__ float s1[8], s2[8];
    __shared__ float mb[2];
    float sum = x, sq = x * x;
    for (int off = 32; off; off >>= 1) {
        sum += __shfl_down(sum, off);
        sq  += __shfl_down(sq,  off);
    }
    if (lane == 0) { s1[wv] = sum; s2[wv] = sq; }
    __syncthreads();
    if (t == 0) {
        float a = 0.f, b = 0.f;
        for (int i = 0; i < 8; ++i) { a += s1[i]; b += s2[i]; }
        float mean = a / (float)DD;
        float var = b / (float)DD - mean * mean;
        mb[0] = mean;
        mb[1] = rsqrtf(var + LNEPS);
    }
    __syncthreads();
    h[idx] = (x - mb[0]) * mb[1] * gw[t] + bw[t];
}

// ======================= head =======================
__global__ void col_mean_part(const float* __restrict__ h, float* __restrict__ partial) {
    int col = blockIdx.x * 256 + threadIdx.x;
    int r0 = blockIdx.y * 20;
    float s = 0.f;
    #pragma unroll
    for (int r = 0; r < 20; ++r) s += h[(size_t)(r0 + r) * DD + col];
    partial[(size_t)blockIdx.y * DD + col] = s;
}

__global__ void head_kernel(const float* __restrict__ partial,
                            const float* __restrict__ hw,
                            const float* __restrict__ hb, float* __restrict__ out) {
    __shared__ float gs[DD];
    __shared__ float r[4];
    __shared__ float bmx, bsum;
    int t = threadIdx.x;
    for (int d = t; d < DD; d += 256) {
        float s = 0.f;
        #pragma unroll
        for (int p = 0; p < 25; ++p) s += partial[(size_t)p * DD + d];
        gs[d] = s / (float)NN;
    }
    __syncthreads();
    float acc = hb[t];
    #pragma unroll 16
    for (int d = 0; d < DD; ++d) acc += gs[d] * hw[(size_t)d * NC + t];
    int lane = t & 63, wv = t >> 6;
    float mx = acc;
    for (int off = 32; off; off >>= 1) mx = fmaxf(mx, __shfl_down(mx, off));
    if (lane == 0) r[wv] = mx;
    __syncthreads();
    if (t == 0) bmx = fmaxf(fmaxf(r[0], r[1]), fmaxf(r[2], r[3]));
    __syncthreads();
    float e = expf(acc - bmx);
    float s = e;
    for (int off = 32; off; off >>= 1) s += __shfl_down(s, off);
    if (lane == 0) r[wv] = s;
    __syncthreads();
    if (t == 0) bsum = 1.f / (r[0] + r[1] + r[2] + r[3]);
    __syncthreads();
    float pv = e * bsum;
    for (int b = 0; b < NB; ++b) out[(size_t)b * NC + t] = pv;
}

extern "C" void kernel_launch(void* const* d_in, const int* in_sizes, int n_in,
                              void* d_out, int out_size, void* d_ws, size_t ws_size,
                              hipStream_t stream) {
    const float* ln_in_b = (const float*)d_in[2];
    const float* patch_W = (const float*)d_in[3];
    const float* patch_b = (const float*)d_in[4];
    const float* pos_emb = (const float*)d_in[5];
    const float* Wq = (const float*)d_in[6];
    const float* bq = (const float*)d_in[7];
    const float* Wk = (const float*)d_in[8];
    const float* bk = (const float*)d_in[9];
    const float* Wv = (const float*)d_in[10];
    const float* bv = (const float*)d_in[11];
    const float* Wo = (const float*)d_in[12];
    const float* bo = (const float*)d_in[13];
    const float* Wc = (const float*)d_in[14];
    const float* bc = (const float*)d_in[15];
    const float* ln1_g = (const float*)d_in[16];
    const float* ln1_b = (const float*)d_in[17];
    const float* W1 = (const float*)d_in[18];
    const float* b1 = (const float*)d_in[19];
    const float* W2 = (const float*)d_in[20];
    const float* b2 = (const float*)d_in[21];
    const float* ln2_g = (const float*)d_in[22];
    const float* ln2_b = (const float*)d_in[23];
    const float* head_W = (const float*)d_in[24];
    const float* head_b = (const float*)d_in[25];
    float* out = (float*)d_out;

    // workspace (floats), aliased: qkvP shares `part`; oPart/ml share `f`.
    float* ws = (float*)d_ws;
    float* h      = ws;                  // 256000
    float* csum   = h + 256000;          // 1024
    float* qkvAll = csum + 1024;         // 420000 (unused this round)
    float* oAll   = qkvAll + 420000;     // 140000 (unused this round)
    float* aAll   = oAll + 140000;       // 448000
    float* f      = aAll + 448000;       // 1024000  (also oPart+ml)
    float* part   = f + 1024000;         // 4194304  (also qkvP 1680000)
    float* headp  = part + 4194304;      // 12800
    float* oPart  = f;                   // 4*140000 = 560000
    float* mPart  = f + 560000;          // 4*4384
    float* lPart  = mPart + 4 * MLSZ;    // 4*4384
    float* qkvP   = part;                // 4*420000 = 1680000

    colsum_kernel<<<1, 512, 0, stream>>>(patch_W, csum);
    init_h<<<(NN * DD + 255) / 256, 256, 0, stream>>>(csum, patch_b, pos_emb, ln_in_b, h);

    for (int l = 0; l < NL; ++l) {
        qkv_part<<<dim3(8, 4, 12), 256, 0, stream>>>(h, Wq, Wk, Wv, qkvP, l);
        attn_split<<<dim3(8, HSC, 7), 256, 0, stream>>>(qkvP, bq, bk, bv,
                                                        oPart, mPart, lPart, l);
        wo_combine<<<dim3(8, 4, 3), 256, 0, stream>>>(oPart, mPart, lPart,
                                                      Wo, bo, aAll, l);
        comb_part<<<dim3(8, 4, 12), 256, 0, stream>>>(
            aAll, Wc + (size_t)l * 3 * DD * DD, part);
        reduce_add_ln<<<NN, DD, 0, stream>>>(part, 12, bc + (size_t)l * DD, h,
                                             ln1_g + (size_t)l * DD, ln1_b + (size_t)l * DD);
        w1_part<<<dim3(32, 4, 4), 256, 0, stream>>>(
            h, W1 + (size_t)l * DD * FF, part);
        w1_reduce<<<(NN * FF + 255) / 256, 256, 0, stream>>>(
            part, b1 + (size_t)l * FF, f);
        w2_part<<<dim3(8, 4, 16), 256, 0, stream>>>(f, W2 + (size_t)l * FF * DD, part);
        reduce_add_ln<<<NN, DD, 0, stream>>>(part, 16, b2 + (size_t)l * DD, h,
                                             ln2_g + (size_t)l * DD, ln2_b + (size_t)l * DD);
    }
    col_mean_part<<<dim3(2, 25), 256, 0, stream>>>(h, headp);
    head_kernel<<<1, 256, 0, stream>>>(headp, head_W, head_b, out);
}

// Round 10
// 881.566 us; speedup vs baseline: 1.1612x; 1.1612x over previous
//
#include <hip/hip_runtime.h>
#include <math.h>

// Model constants: B=32, T=50000, P=100, D=512, H=16, L=6, C=256
// SCALES=[1,2,4], HS=5 heads/scale, KD=32, N=500 patches, FF=2048, EPS=1e-3.
//
// KEY INSIGHT (round 0, verified): first layernorm is over a size-1 axis ->
// output == ln_in_b[0] everywhere. h is batch-independent; network runs once
// on (500 x 512); final row broadcast x32.
//
// Ledger: R6 bf16-MFMA. R7/8 k-splits 999->839. R9 refused 1122 (staging
// serialized). R10 branch-free staging 965. R11 sched_barrier 864 (anti-
// pattern). R12 splits+branch-free 803. R13 deeper splits 797 (null ->
// fixed dispatch cost dominates). R14: qkv_reduce->attn fusion REGRESSED
// to 1024 (attn FETCH 34MB/dispatch: 280 blocks x 4 partial slices = 4x
// read amplification); wo_combine fusion saved ~30us (1024 < 797+258
// attn-only estimate).
// Round 15 (this round): revert fusion (a) — restore qkv_reduce (reads
// partials ONCE, writes reduced qkvAll) and round-13 attn_split reading
// qkvAll. KEEP fusion (b) wo_combine (branch-free, no sched_barrier).

#define DD 512
#define NN 500
#define HSC 5
#define KDD 32
#define QKVN 160
#define QKV3 480
#define FF 2048
#define NL 6
#define NC 256
#define NB 32
#define LNEPS 1e-3f
#define BM 128
#define BN 64
#define KCHB 64

// aAll sub-buffer offsets (floats)
#define AOFF1 256000
#define AOFF2 384000
// total attn rows over scales (500+250+125)
#define RTOT 875
#define OSZ 140000      // RTOT*160
#define MLSZ 4384       // RTOT*5 rounded up
#define QSP 420000      // qkv partial slice stride (floats)

typedef __attribute__((ext_vector_type(8))) short bf16x8;
typedef __attribute__((ext_vector_type(4))) float f32x4;

__device__ __forceinline__ float gelu_exact(float x) {
    return 0.5f * x * (1.0f + erff(x * 0.70710678118654752f));
}

// pack two f32 -> two bf16 (RNE) in one instr
__device__ __forceinline__ unsigned int pkbf(float a, float b) {
    unsigned int r;
    asm("v_cvt_pk_bf16_f32 %0, %1, %2" : "=v"(r) : "v"(a), "v"(b));
    return r;
}

// ======================= MFMA GEMM core =======================
// Tile: BM=128 x BN=64, 256 threads = 4 waves (2x2), K-chunk 64.
// A fp32 [M][K] (lda), POOL row-pooling or 3-scale GATHER (compile-time);
// B fp32 [K][N]: caller resolves per-thread column -> Bcol (always valid).
// ALL loads unconditional/branch-free: rows clamped to M-1 (dup rows never
// stored); TAIL>0: addresses clamped to klim, tail values masked via
// cndmask (A side only; B garbage x A-zero = 0).
// LDS row pitch 128B, swizzle byte ^= ((row&7)<<4) -> conflict-free b128.

template<int POOL, int GATHER, int TAIL>
__device__ __forceinline__ void mstage(
        const float* __restrict__ A, int lda,
        const float* __restrict__ Bcol, int ldb,
        int M, int bm, int k0, int klim,
        int ar4, int akq, int bkq,
        float4 (&aR)[2][4], float4 (&bR)[4]) {
    #pragma unroll
    for (int p = 0; p < 2; ++p) {
        int row = min(bm + ar4 + p * 64, M - 1);
        const float* ap;
        if (!GATHER) {
            ap = A + (size_t)row * POOL * lda;
        } else {
            int si = k0 >> 9;
            ap = A + (si == 0 ? 0 : (si == 1 ? AOFF1 : AOFF2))
               + (size_t)(row >> si) * DD - (size_t)(k0 & ~(DD - 1));
        }
        #pragma unroll
        for (int i = 0; i < 4; ++i) {
            int kk = akq + i * 4;
            int kg = TAIL ? min(k0 + kk, klim - 4) : (k0 + kk);
            float4 v = *(const float4*)(ap + kg);
            #pragma unroll
            for (int t = 1; t < POOL; ++t) {
                float4 u = *(const float4*)(ap + kg + (size_t)t * lda);
                v.x += u.x; v.y += u.y; v.z += u.z; v.w += u.w;
            }
            if (POOL > 1) {
                const float ip = 1.0f / (float)POOL;
                v.x *= ip; v.y *= ip; v.z *= ip; v.w *= ip;
            }
            if (TAIL) {
                bool ok = (k0 + kk) < klim;       // cndmask, no branch
                v.x = ok ? v.x : 0.f; v.y = ok ? v.y : 0.f;
                v.z = ok ? v.z : 0.f; v.w = ok ? v.w : 0.f;
            }
            aR[p][i] = v;
        }
    }
    #pragma unroll
    for (int i = 0; i < 4; ++i) {
        int kr = TAIL ? min(k0 + bkq + i, klim - 1) : (k0 + bkq + i);
        bR[i] = *(const float4*)(Bcol + (size_t)kr * ldb);
    }
}

template<int POOL, int GATHER, int TAIL>
__device__ __forceinline__ void mfma_core(
        const float* __restrict__ A, int lda,
        const float* __restrict__ Bcol, int ldb,
        int M, int bm, int ks, int nch, int klim, f32x4 (&acc)[4][2]) {
    __shared__ __align__(16) unsigned short As[128 * 64];   // 16 KB
    __shared__ __align__(16) unsigned short Bs[64 * 64];    // 8 KB
    const int tid = threadIdx.x;
    const int ar4 = tid >> 2, akq = (tid & 3) * 16;   // A: 2 rows, 16 k each
    const int bkq = (tid >> 4) * 4, bn4 = tid & 15;   // B: 4 k-rows, col quad
    const int lane = tid & 63, wid = tid >> 6;
    const int wm = wid >> 1, wn = wid & 1;

    float4 aR[2][4], bR[4];
    mstage<POOL, GATHER, TAIL>(A, lda, Bcol, ldb, M, bm, ks, klim,
                               ar4, akq, bkq, aR, bR);

    for (int c = 0; c < nch; ++c) {
        __syncthreads();
        // ---- regs -> LDS (cvt to bf16, swizzled) ----
        #pragma unroll
        for (int p = 0; p < 2; ++p) {
            int r = ar4 + p * 64;
            int swz = (r & 7) << 4;
            char* base = (char*)As + r * 128;
            #pragma unroll
            for (int i = 0; i < 4; ++i) {
                int cb = (akq + i * 4) * 2;
                *(uint2*)(base + (cb ^ swz)) = make_uint2(
                    pkbf(aR[p][i].x, aR[p][i].y), pkbf(aR[p][i].z, aR[p][i].w));
            }
        }
        {
            const float* b0 = (const float*)&bR[0];
            const float* b1 = (const float*)&bR[1];
            const float* b2 = (const float*)&bR[2];
            const float* b3 = (const float*)&bR[3];
            #pragma unroll
            for (int j = 0; j < 4; ++j) {
                int nrow = bn4 * 4 + j;
                char* base = (char*)Bs + nrow * 128;
                *(uint2*)(base + ((bkq * 2) ^ ((nrow & 7) << 4))) = make_uint2(
                    pkbf(b0[j], b1[j]), pkbf(b2[j], b3[j]));
            }
        }
        __syncthreads();
        if (c + 1 < nch)
            mstage<POOL, GATHER, TAIL>(A, lda, Bcol, ldb, M, bm,
                                       ks + (c + 1) * KCHB, klim,
                                       ar4, akq, bkq, aR, bR);
        // ---- compute: 2 k-steps of 32, 8 MFMA each per wave ----
        #pragma unroll
        for (int half = 0; half < 2; ++half) {
            const int kb = (half * 32 + (lane >> 4) * 8) * 2;
            bf16x8 af[4], bf[2];
            #pragma unroll
            for (int m = 0; m < 4; ++m) {
                int r = wm * 64 + m * 16 + (lane & 15);
                af[m] = *(const bf16x8*)((const char*)As + r * 128 + (kb ^ ((r & 7) << 4)));
            }
            #pragma unroll
            for (int n = 0; n < 2; ++n) {
                int r = wn * 32 + n * 16 + (lane & 15);
                bf[n] = *(const bf16x8*)((const char*)Bs + r * 128 + (kb ^ ((r & 7) << 4)));
            }
            #pragma unroll
            for (int m = 0; m < 4; ++m)
                #pragma unroll
                for (int n = 0; n < 2; ++n)
                    acc[m][n] = __builtin_amdgcn_mfma_f32_16x16x32_bf16(
                        af[m], bf[n], acc[m][n], 0, 0, 0);
        }
    }
}

#define MACC_INIT(acc) { _Pragma("unroll") for (int m_ = 0; m_ < 4; ++m_) \
    _Pragma("unroll") for (int n_ = 0; n_ < 2; ++n_) \
    _Pragma("unroll") for (int j_ = 0; j_ < 4; ++j_) acc[m_][n_][j_] = 0.f; }

// ======================= setup =======================
__global__ void colsum_kernel(const float* __restrict__ pw, float* __restrict__ csum) {
    int d = blockIdx.x * blockDim.x + threadIdx.x;
    if (d < DD) {
        float s = 0.f;
        for (int p = 0; p < 100; ++p) s += pw[p * DD + d];
        csum[d] = s;
    }
}

__global__ void init_h(const float* __restrict__ csum, const float* __restrict__ pb,
                       const float* __restrict__ pos, const float* __restrict__ lnb,
                       float* __restrict__ h) {
    int idx = blockIdx.x * 256 + threadIdx.x;
    if (idx >= NN * DD) return;
    int d = idx & (DD - 1);
    h[idx] = lnb[0] * csum[d] + pb[d] + pos[idx];
}

// ======================= QKV partial (all scales, k-split S=4) =============
// grid (8, 4, 12): x = 64-col tile over 480 (q|k|v), y = 128-row tile,
// z = scale*4 + ps (k quarter of 128). Bias applied in qkv_reduce.
__global__ __launch_bounds__(256, 2) void qkv_part(
        const float* __restrict__ h,
        const float* __restrict__ Wq, const float* __restrict__ Wk,
        const float* __restrict__ Wv,
        float* __restrict__ part, int l) {
    int scale = blockIdx.z >> 2, ps = blockIdx.z & 3;
    int n = NN >> scale;
    int bm = blockIdx.y * BM;
    if (bm >= n) return;
    int bn = blockIdx.x * BN;
    size_t w = (size_t)(l * 3 + scale);
    int tid = threadIdx.x;
    int col = min(bn + (tid & 15) * 4, QKV3 - 4);
    int which = (col >= 320) ? 2 : ((col >= 160) ? 1 : 0);
    const float* Wsel = (which == 0) ? Wq : ((which == 1) ? Wk : Wv);
    const float* Bcol = Wsel + w * DD * QKVN + (col - which * QKVN);
    float* outb = part + (size_t)ps * QSP
                + (scale == 0 ? 0 : (scale == 1 ? 240000 : 360000));

    f32x4 acc[4][2];
    MACC_INIT(acc);
    if (scale == 0)
        mfma_core<1, 0, 0>(h, DD, Bcol, QKVN, n, bm, ps * 128, 2, DD, acc);
    else if (scale == 1)
        mfma_core<2, 0, 0>(h, DD, Bcol, QKVN, n, bm, ps * 128, 2, DD, acc);
    else
        mfma_core<4, 0, 0>(h, DD, Bcol, QKVN, n, bm, ps * 128, 2, DD, acc);

    int lane = tid & 63, wid = tid >> 6, wm = wid >> 1, wn = wid & 1;
    #pragma unroll
    for (int q = 0; q < 2; ++q) {
        int cb = bn + wn * 32 + q * 16;
        if (cb >= QKV3) continue;
        int c2 = cb + (lane & 15);
        #pragma unroll
        for (int m = 0; m < 4; ++m) {
            int r0 = bm + wm * 64 + m * 16 + ((lane >> 4) << 2);
            #pragma unroll
            for (int j = 0; j < 4; ++j) {
                int r = r0 + j;
                if (r < n) outb[(size_t)r * QKV3 + c2] = acc[m][q][j];
            }
        }
    }
}

__global__ void qkv_reduce(const float* __restrict__ part,
                           const float* __restrict__ bq,
                           const float* __restrict__ bk,
                           const float* __restrict__ bv,
                           float* __restrict__ qkvAll, int l) {
    int idx = blockIdx.x * 256 + threadIdx.x;
    if (idx >= 420000) return;
    int scale, base;
    if (idx < 240000) { scale = 0; base = 0; }
    else if (idx < 360000) { scale = 1; base = 240000; }
    else { scale = 2; base = 360000; }
    int rowrem = (idx - base) % QKV3;
    int which = rowrem / QKVN;
    int col = rowrem - which * QKVN;
    float v = part[idx] + part[QSP + idx]
            + part[2 * QSP + idx] + part[3 * QSP + idx];
    v += ((which == 0) ? bq : (which == 1 ? bk : bv))[(size_t)(l * 3 + scale) * QKVN + col];
    qkvAll[idx] = v;
}

// ======================= attention: key-split flash =======================
__global__ __launch_bounds__(256, 2) void attn_split(
        const float* __restrict__ qkvAll, float* __restrict__ oPart,
        float* __restrict__ mPart, float* __restrict__ lPart) {
    int z = blockIdx.z;
    int scale, sp;
    if (z < 4)      { scale = 0; sp = z; }
    else if (z < 6) { scale = 1; sp = z - 4; }
    else            { scale = 2; sp = 0; }
    int n = NN >> scale;
    int qt = blockIdx.x;
    if (qt * 64 >= n) return;
    int hh = blockIdx.y;
    int ks = sp * 128;
    int ke = min(n, ks + 128);
    const float* qkv = qkvAll + (scale == 0 ? 0 : (scale == 1 ? 240000 : 360000));
    int rowb = (scale == 0 ? 0 : (scale == 1 ? 500 : 750));

    int tid = threadIdx.x;
    int kg = tid & 7, qq = tid >> 3;
    int q0 = qt * 64 + qq, q1 = q0 + 32;
    bool ok0 = q0 < n, ok1 = q1 < n;

    float qa[32], qb[32];
    {
        const float* p0 = qkv + (size_t)(ok0 ? q0 : 0) * QKV3 + hh * KDD;
        const float* p1 = qkv + (size_t)(ok1 ? q1 : 0) * QKV3 + hh * KDD;
        #pragma unroll
        for (int c4 = 0; c4 < 8; ++c4) {
            float4 v0 = *(const float4*)(p0 + c4 * 4);
            float4 v1 = *(const float4*)(p1 + c4 * 4);
            qa[c4 * 4] = v0.x; qa[c4 * 4 + 1] = v0.y; qa[c4 * 4 + 2] = v0.z; qa[c4 * 4 + 3] = v0.w;
            qb[c4 * 4] = v1.x; qb[c4 * 4 + 1] = v1.y; qb[c4 * 4 + 2] = v1.z; qb[c4 * 4 + 3] = v1.w;
        }
    }

    __shared__ float Ks[64][36];
    __shared__ float Vs[64][36];
    float o0[32], o1[32];
    #pragma unroll
    for (int c = 0; c < 32; ++c) { o0[c] = 0.f; o1[c] = 0.f; }
    float m0 = -1e30f, m1 = -1e30f, l0 = 0.f, l1 = 0.f;

    int srow = tid >> 2, scol = tid & 3;

    for (int kc = ks; kc < ke; kc += 64) {
        __syncthreads();
        int krow = kc + srow;
        bool ok = krow < ke;
        const float* kp = qkv + (size_t)(ok ? krow : 0) * QKV3 + QKVN + hh * KDD;
        #pragma unroll
        for (int half = 0; half < 2; ++half) {
            int cc = (half * 4 + scol) * 4;
            float4 kv = ok ? *(const float4*)(kp + cc) : make_float4(0.f, 0.f, 0.f, 0.f);
            float4 vv = ok ? *(const float4*)(kp + QKVN + cc) : make_float4(0.f, 0.f, 0.f, 0.f);
            Ks[srow][cc] = kv.x; Ks[srow][cc + 1] = kv.y; Ks[srow][cc + 2] = kv.z; Ks[srow][cc + 3] = kv.w;
            Vs[srow][cc] = vv.x; Vs[srow][cc + 1] = vv.y; Vs[srow][cc + 2] = vv.z; Vs[srow][cc + 3] = vv.w;
        }
        __syncthreads();

        float p0[8], p1[8];
        float cm = -1e30f;
        #pragma unroll
        for (int jj = 0; jj < 8; ++jj) {
            int j = jj * 8 + kg;
            float s0 = 0.f, s1 = 0.f;
            #pragma unroll
            for (int c4 = 0; c4 < 8; ++c4) {
                float4 kv = *(const float4*)&Ks[j][c4 * 4];
                s0 += qa[c4 * 4] * kv.x + qa[c4 * 4 + 1] * kv.y
                    + qa[c4 * 4 + 2] * kv.z + qa[c4 * 4 + 3] * kv.w;
                s1 += qb[c4 * 4] * kv.x + qb[c4 * 4 + 1] * kv.y
                    + qb[c4 * 4 + 2] * kv.z + qb[c4 * 4 + 3] * kv.w;
            }
            s0 *= 0.17677669529663687f;
            s1 *= 0.17677669529663687f;
            if (kc + j >= ke) { s0 = -1e30f; s1 = -1e30f; }
            p0[jj] = s0; p1[jj] = s1;
            cm = fmaxf(cm, fmaxf(s0, s1));
        }
        cm = fmaxf(cm, __shfl_xor(cm, 1));
        cm = fmaxf(cm, __shfl_xor(cm, 2));
        cm = fmaxf(cm, __shfl_xor(cm, 4));

        float mn0 = fmaxf(m0, cm), mn1 = fmaxf(m1, cm);
        float al0 = expf(m0 - mn0), al1 = expf(m1 - mn1);
        m0 = mn0; m1 = mn1;
        float ls0 = 0.f, ls1 = 0.f;
        #pragma unroll
        for (int jj = 0; jj < 8; ++jj) {
            p0[jj] = expf(p0[jj] - mn0); ls0 += p0[jj];
            p1[jj] = expf(p1[jj] - mn1); ls1 += p1[jj];
        }
        l0 = l0 * al0 + ls0;
        l1 = l1 * al1 + ls1;
        #pragma unroll
        for (int c = 0; c < 32; ++c) { o0[c] *= al0; o1[c] *= al1; }
        #pragma unroll
        for (int jj = 0; jj < 8; ++jj) {
            int j = jj * 8 + kg;
            float w0 = p0[jj], w1 = p1[jj];
            #pragma unroll
            for (int c4 = 0; c4 < 8; ++c4) {
                float4 vv = *(const float4*)&Vs[j][c4 * 4];
                o0[c4 * 4]     += w0 * vv.x; o0[c4 * 4 + 1] += w0 * vv.y;
                o0[c4 * 4 + 2] += w0 * vv.z; o0[c4 * 4 + 3] += w0 * vv.w;
                o1[c4 * 4]     += w1 * vv.x; o1[c4 * 4 + 1] += w1 * vv.y;
                o1[c4 * 4 + 2] += w1 * vv.z; o1[c4 * 4 + 3] += w1 * vv.w;
            }
        }
    }
    #pragma unroll
    for (int st = 1; st < 8; st <<= 1) {
        l0 += __shfl_xor(l0, st);
        l1 += __shfl_xor(l1, st);
        #pragma unroll
        for (int c = 0; c < 32; ++c) {
            o0[c] += __shfl_xor(o0[c], st);
            o1[c] += __shfl_xor(o1[c], st);
        }
    }
    if (kg == 0) {
        float* ob = oPart + (size_t)sp * OSZ;
        if (ok0) {
            int r = rowb + q0;
            float* op = ob + (size_t)r * QKVN + hh * KDD;
            #pragma unroll
            for (int c4 = 0; c4 < 8; ++c4) {
                float4 v; v.x = o0[c4*4]; v.y = o0[c4*4+1]; v.z = o0[c4*4+2]; v.w = o0[c4*4+3];
                *(float4*)(op + c4 * 4) = v;
            }
            mPart[sp * MLSZ + r * HSC + hh] = m0;
            lPart[sp * MLSZ + r * HSC + hh] = l0;
        }
        if (ok1) {
            int r = rowb + q1;
            float* op = ob + (size_t)r * QKVN + hh * KDD;
            #pragma unroll
            for (int c4 = 0; c4 < 8; ++c4) {
                float4 v; v.x = o1[c4*4]; v.y = o1[c4*4+1]; v.z = o1[c4*4+2]; v.w = o1[c4*4+3];
                *(float4*)(op + c4 * 4) = v;
            }
            mPart[sp * MLSZ + r * HSC + hh] = m1;
            lPart[sp * MLSZ + r * HSC + hh] = l1;
        }
    }
}

// ======================= Wo + combine fused (all scales) ===================
// Combine weights w_s=exp(m_s-M)/L in LDS; A-staging combines <=4 oPart
// slices on the fly. Branch-free; NO sched_barrier (m141).
__global__ __launch_bounds__(256, 2) void wo_combine(
        const float* __restrict__ oPart, const float* __restrict__ mPart,
        const float* __restrict__ lPart, const float* __restrict__ Wo,
        const float* __restrict__ bo, float* __restrict__ aAll, int l) {
    int z = blockIdx.z;
    int n = NN >> z;
    int ns = 4 >> z;
    int bm = blockIdx.y * BM;
    if (bm >= n) return;
    int bn = blockIdx.x * BN;
    int rowb = (z == 0 ? 0 : (z == 1 ? 500 : 750));
    size_t w = (size_t)(l * 3 + z);
    int tid = threadIdx.x;
    const float* Bcol = Wo + w * QKVN * DD + bn + (tid & 15) * 4;
    float* C = aAll + (z == 0 ? 0 : (z == 1 ? AOFF1 : AOFF2));

    __shared__ __align__(16) unsigned short As[128 * 64];   // 16 KB
    __shared__ __align__(16) unsigned short Bs[64 * 64];    // 8 KB
    __shared__ __align__(16) float Wcm[128][24];            // 12 KB

    for (int it = tid; it < 128 * HSC; it += 256) {
        int lrow = it / HSC, hh = it - lrow * HSC;
        float w4[4] = {0.f, 0.f, 0.f, 0.f};
        int row = bm + lrow;
        if (row < n) {
            int gr = rowb + row;
            float M = -1e30f;
            for (int s = 0; s < ns; ++s)
                M = fmaxf(M, mPart[s * MLSZ + gr * HSC + hh]);
            float L = 0.f;
            for (int s = 0; s < ns; ++s) {
                float e = expf(mPart[s * MLSZ + gr * HSC + hh] - M);
                w4[s] = e;
                L += e * lPart[s * MLSZ + gr * HSC + hh];
            }
            float inv = 1.f / L;
            for (int s = 0; s < ns; ++s) w4[s] *= inv;
        }
        Wcm[lrow][hh * 4 + 0] = w4[0];
        Wcm[lrow][hh * 4 + 1] = w4[1];
        Wcm[lrow][hh * 4 + 2] = w4[2];
        Wcm[lrow][hh * 4 + 3] = w4[3];
    }
    __syncthreads();

    const int ar4 = tid >> 2, akq = (tid & 3) * 16;
    const int bkq = (tid >> 4) * 4, bn4 = tid & 15;
    const int lane = tid & 63, wid = tid >> 6;
    const int wm = wid >> 1, wn = wid & 1;

    f32x4 acc[4][2];
    MACC_INIT(acc);
    float4 aR[2][4], bR[4];

    auto stage = [&](int k0) {
        int krem = QKVN - k0;
        #pragma unroll
        for (int p = 0; p < 2; ++p) {
            int row = min(bm + ar4 + p * 64, n - 1);
            int lrowc = row - bm;
            #pragma unroll
            for (int i = 0; i < 4; ++i) {
                int kk = akq + i * 4;
                int k = min(k0 + kk, QKVN - 4);
                int hh = min(k >> 5, 4);
                float4 w4 = *(const float4*)&Wcm[lrowc][hh * 4];
                size_t off = (size_t)(rowb + row) * QKVN + k;
                float4 a0 = *(const float4*)(oPart + off);
                float4 v;
                v.x = w4.x * a0.x; v.y = w4.x * a0.y;
                v.z = w4.x * a0.z; v.w = w4.x * a0.w;
                if (ns > 1) {
                    float4 a1 = *(const float4*)(oPart + OSZ + off);
                    v.x += w4.y * a1.x; v.y += w4.y * a1.y;
                    v.z += w4.y * a1.z; v.w += w4.y * a1.w;
                }
                if (ns > 2) {
                    float4 a2 = *(const float4*)(oPart + 2 * OSZ + off);
                    float4 a3 = *(const float4*)(oPart + 3 * OSZ + off);
                    v.x += w4.z * a2.x + w4.w * a3.x;
                    v.y += w4.z * a2.y + w4.w * a3.y;
                    v.z += w4.z * a2.z + w4.w * a3.z;
                    v.w += w4.z * a2.w + w4.w * a3.w;
                }
                bool kv_ = kk < krem;
                v.x = kv_ ? v.x : 0.f; v.y = kv_ ? v.y : 0.f;
                v.z = kv_ ? v.z : 0.f; v.w = kv_ ? v.w : 0.f;
                aR[p][i] = v;
            }
        }
        #pragma unroll
        for (int i = 0; i < 4; ++i) {
            int krow = min(k0 + bkq + i, QKVN - 1);
            bR[i] = *(const float4*)(Bcol + (size_t)krow * DD);
        }
    };

    const int nch = 3;   // K=160: chunks of 64,64,32
    stage(0);
    for (int c = 0; c < nch; ++c) {
        __syncthreads();
        #pragma unroll
        for (int p = 0; p < 2; ++p) {
            int r = ar4 + p * 64;
            int swz = (r & 7) << 4;
            char* base = (char*)As + r * 128;
            #pragma unroll
            for (int i = 0; i < 4; ++i) {
                int cb = (akq + i * 4) * 2;
                *(uint2*)(base + (cb ^ swz)) = make_uint2(
                    pkbf(aR[p][i].x, aR[p][i].y), pkbf(aR[p][i].z, aR[p][i].w));
            }
        }
        {
            const float* b0 = (const float*)&bR[0];
            const float* b1 = (const float*)&bR[1];
            const float* b2 = (const float*)&bR[2];
            const float* b3 = (const float*)&bR[3];
            #pragma unroll
            for (int j = 0; j < 4; ++j) {
                int nrow = bn4 * 4 + j;
                char* base = (char*)Bs + nrow * 128;
                *(uint2*)(base + ((bkq * 2) ^ ((nrow & 7) << 4))) = make_uint2(
                    pkbf(b0[j], b1[j]), pkbf(b2[j], b3[j]));
            }
        }
        __syncthreads();
        if (c + 1 < nch) stage((c + 1) * KCHB);
        #pragma unroll
        for (int half = 0; half < 2; ++half) {
            const int kb = (half * 32 + (lane >> 4) * 8) * 2;
            bf16x8 af[4], bf[2];
            #pragma unroll
            for (int m = 0; m < 4; ++m) {
                int r = wm * 64 + m * 16 + (lane & 15);
                af[m] = *(const bf16x8*)((const char*)As + r * 128 + (kb ^ ((r & 7) << 4)));
            }
            #pragma unroll
            for (int n2 = 0; n2 < 2; ++n2) {
                int r = wn * 32 + n2 * 16 + (lane & 15);
                bf[n2] = *(const bf16x8*)((const char*)Bs + r * 128 + (kb ^ ((r & 7) << 4)));
            }
            #pragma unroll
            for (int m = 0; m < 4; ++m)
                #pragma unroll
                for (int n2 = 0; n2 < 2; ++n2)
                    acc[m][n2] = __builtin_amdgcn_mfma_f32_16x16x32_bf16(
                        af[m], bf[n2], acc[m][n2], 0, 0, 0);
        }
    }

    const float* bias = bo + w * DD;
    #pragma unroll
    for (int q = 0; q < 2; ++q) {
        int c2 = bn + wn * 32 + q * 16 + (lane & 15);
        float bv_ = bias[c2];
        #pragma unroll
        for (int m = 0; m < 4; ++m) {
            int r0 = bm + wm * 64 + m * 16 + ((lane >> 4) << 2);
            #pragma unroll
            for (int j = 0; j < 4; ++j) {
                int r = r0 + j;
                if (r < n) C[(size_t)r * DD + c2] = acc[m][q][j] + bv_;
            }
        }
    }
}

// ======================= comb partial (gather-A, k-split S=12) =============
__global__ __launch_bounds__(256, 2) void comb_part(
        const float* __restrict__ aAll, const float* __restrict__ Wc,
        float* __restrict__ part) {
    int zz = blockIdx.z;
    int bm = blockIdx.y * BM, bn = blockIdx.x * BN;
    int tid = threadIdx.x;
    const float* Bcol = Wc + bn + (tid & 15) * 4;
    f32x4 acc[4][2];
    MACC_INIT(acc);
    mfma_core<1, 1, 0>(aAll, DD, Bcol, DD, NN, bm, zz * 128, 2, 1536, acc);

    float* pz = part + (size_t)zz * NN * DD;
    int lane = tid & 63, wid = tid >> 6, wm = wid >> 1, wn = wid & 1;
    #pragma unroll
    for (int q = 0; q < 2; ++q) {
        int c2 = bn + wn * 32 + q * 16 + (lane & 15);
        #pragma unroll
        for (int m = 0; m < 4; ++m) {
            int r0 = bm + wm * 64 + m * 16 + ((lane >> 4) << 2);
            #pragma unroll
            for (int j = 0; j < 4; ++j) {
                int r = r0 + j;
                if (r < NN) pz[(size_t)r * DD + c2] = acc[m][q][j];
            }
        }
    }
}

// ======================= W1 partial (k-split S=4) ==========================
__global__ __launch_bounds__(256, 2) void w1_part(
        const float* __restrict__ h, const float* __restrict__ W1,
        float* __restrict__ part) {
    int sp = blockIdx.z;
    int bm = blockIdx.y * BM, bn = blockIdx.x * BN;
    int tid = threadIdx.x;
    const float* Bcol = W1 + bn + (tid & 15) * 4;
    f32x4 acc[4][2];
    MACC_INIT(acc);
    mfma_core<1, 0, 0>(h, DD, Bcol, FF, NN, bm, sp * 128, 2, DD, acc);

    float* pz = part + (size_t)sp * NN * FF;
    int lane = tid & 63, wid = tid >> 6, wm = wid >> 1, wn = wid & 1;
    #pragma unroll
    for (int q = 0; q < 2; ++q) {
        int c2 = bn + wn * 32 + q * 16 + (lane & 15);
        #pragma unroll
        for (int m = 0; m < 4; ++m) {
            int r0 = bm + wm * 64 + m * 16 + ((lane >> 4) << 2);
            #pragma unroll
            for (int j = 0; j < 4; ++j) {
                int r = r0 + j;
                if (r < NN) pz[(size_t)r * FF + c2] = acc[m][q][j];
            }
        }
    }
}

__global__ void w1_reduce(const float* __restrict__ part,
                          const float* __restrict__ b1, float* __restrict__ f) {
    int idx = blockIdx.x * 256 + threadIdx.x;
    if (idx >= NN * FF) return;
    float v = part[idx] + part[NN * FF + idx]
            + part[2 * NN * FF + idx] + part[3 * NN * FF + idx];
    f[idx] = gelu_exact(v + b1[idx & (FF - 1)]);
}

// ======================= W2 partial (k-split S=16) =========================
__global__ __launch_bounds__(256, 2) void w2_part(
        const float* __restrict__ f, const float* __restrict__ W2,
        float* __restrict__ part) {
    int sp = blockIdx.z;
    int bm = blockIdx.y * BM, bn = blockIdx.x * BN;
    int tid = threadIdx.x;
    const float* Bcol = W2 + bn + (tid & 15) * 4;
    f32x4 acc[4][2];
    MACC_INIT(acc);
    mfma_core<1, 0, 0>(f, FF, Bcol, DD, NN, bm, sp * 128, 2, FF, acc);

    float* pz = part + (size_t)sp * NN * DD;
    int lane = tid & 63, wid = tid >> 6, wm = wid >> 1, wn = wid & 1;
    #pragma unroll
    for (int q = 0; q < 2; ++q) {
        int c2 = bn + wn * 32 + q * 16 + (lane & 15);
        #pragma unroll
        for (int m = 0; m < 4; ++m) {
            int r0 = bm + wm * 64 + m * 16 + ((lane >> 4) << 2);
            #pragma unroll
            for (int j = 0; j < 4; ++j) {
                int r = r0 + j;
                if (r < NN) pz[(size_t)r * DD + c2] = acc[m][q][j];
            }
        }
    }
}

// ======================= fused reduce + bias + residual + LN ===============
__global__ void reduce_add_ln(const float* __restrict__ part, int S,
                              const float* __restrict__ bias,
                              float* __restrict__ h,
                              const float* __restrict__ gw,
                              const float* __restrict__ bw) {
    int row = blockIdx.x, t = threadIdx.x;
    size_t idx = (size_t)row * DD + t;
    float x = h[idx] + bias[t];
    for (int s = 0; s < S; ++s) x += part[(size_t)s * NN * DD + idx];
    int lane = t & 63, wv = t >> 6;
    __shared__ float s1[8], s2[8];
    __shared__ float mb[2];
    float sum = x, sq = x * x;
    for (int off = 32; off; off >>= 1) {
        sum += __shfl_down(sum, off);
        sq  += __shfl_down(sq,  off);
    }
    if (lane == 0) { s1[wv] = sum; s2[wv] = sq; }
    __syncthreads();
    if (t == 0) {
        float a = 0.f, b = 0.f;
        for (int i = 0; i < 8; ++i) { a += s1[i]; b += s2[i]; }
        float mean = a / (float)DD;
        float var = b / (float)DD - mean * mean;
        mb[0] = mean;
        mb[1] = rsqrtf(var + LNEPS);
    }
    __syncthreads();
    h[idx] = (x - mb[0]) * mb[1] * gw[t] + bw[t];
}

// ======================= head =======================
__global__ void col_mean_part(const float* __restrict__ h, float* __restrict__ partial) {
    int col = blockIdx.x * 256 + threadIdx.x;
    int r0 = blockIdx.y * 20;
    float s = 0.f;
    #pragma unroll
    for (int r = 0; r < 20; ++r) s += h[(size_t)(r0 + r) * DD + col];
    partial[(size_t)blockIdx.y * DD + col] = s;
}

__global__ void head_kernel(const float* __restrict__ partial,
                            const float* __restrict__ hw,
                            const float* __restrict__ hb, float* __restrict__ out) {
    __shared__ float gs[DD];
    __shared__ float r[4];
    __shared__ float bmx, bsum;
    int t = threadIdx.x;
    for (int d = t; d < DD; d += 256) {
        float s = 0.f;
        #pragma unroll
        for (int p = 0; p < 25; ++p) s += partial[(size_t)p * DD + d];
        gs[d] = s / (float)NN;
    }
    __syncthreads();
    float acc = hb[t];
    #pragma unroll 16
    for (int d = 0; d < DD; ++d) acc += gs[d] * hw[(size_t)d * NC + t];
    int lane = t & 63, wv = t >> 6;
    float mx = acc;
    for (int off = 32; off; off >>= 1) mx = fmaxf(mx, __shfl_down(mx, off));
    if (lane == 0) r[wv] = mx;
    __syncthreads();
    if (t == 0) bmx = fmaxf(fmaxf(r[0], r[1]), fmaxf(r[2], r[3]));
    __syncthreads();
    float e = expf(acc - bmx);
    float s = e;
    for (int off = 32; off; off >>= 1) s += __shfl_down(s, off);
    if (lane == 0) r[wv] = s;
    __syncthreads();
    if (t == 0) bsum = 1.f / (r[0] + r[1] + r[2] + r[3]);
    __syncthreads();
    float pv = e * bsum;
    for (int b = 0; b < NB; ++b) out[(size_t)b * NC + t] = pv;
}

extern "C" void kernel_launch(void* const* d_in, const int* in_sizes, int n_in,
                              void* d_out, int out_size, void* d_ws, size_t ws_size,
                              hipStream_t stream) {
    const float* ln_in_b = (const float*)d_in[2];
    const float* patch_W = (const float*)d_in[3];
    const float* patch_b = (const float*)d_in[4];
    const float* pos_emb = (const float*)d_in[5];
    const float* Wq = (const float*)d_in[6];
    const float* bq = (const float*)d_in[7];
    const float* Wk = (const float*)d_in[8];
    const float* bk = (const float*)d_in[9];
    const float* Wv = (const float*)d_in[10];
    const float* bv = (const float*)d_in[11];
    const float* Wo = (const float*)d_in[12];
    const float* bo = (const float*)d_in[13];
    const float* Wc = (const float*)d_in[14];
    const float* bc = (const float*)d_in[15];
    const float* ln1_g = (const float*)d_in[16];
    const float* ln1_b = (const float*)d_in[17];
    const float* W1 = (const float*)d_in[18];
    const float* b1 = (const float*)d_in[19];
    const float* W2 = (const float*)d_in[20];
    const float* b2 = (const float*)d_in[21];
    const float* ln2_g = (const float*)d_in[22];
    const float* ln2_b = (const float*)d_in[23];
    const float* head_W = (const float*)d_in[24];
    const float* head_b = (const float*)d_in[25];
    float* out = (float*)d_out;

    // workspace (floats), aliased: qkvP shares `part`; oPart/ml share `f`.
    float* ws = (float*)d_ws;
    float* h      = ws;                  // 256000
    float* csum   = h + 256000;          // 1024
    float* qkvAll = csum + 1024;         // 420000
    float* oAll   = qkvAll + 420000;     // 140000 (unused)
    float* aAll   = oAll + 140000;       // 448000
    float* f      = aAll + 448000;       // 1024000  (also oPart+ml)
    float* part   = f + 1024000;         // 4194304  (also qkvP 1680000)
    float* headp  = part + 4194304;      // 12800
    float* oPart  = f;                   // 4*140000 = 560000
    float* mPart  = f + 560000;          // 4*4384
    float* lPart  = mPart + 4 * MLSZ;    // 4*4384
    float* qkvP   = part;                // 4*420000 = 1680000

    colsum_kernel<<<1, 512, 0, stream>>>(patch_W, csum);
    init_h<<<(NN * DD + 255) / 256, 256, 0, stream>>>(csum, patch_b, pos_emb, ln_in_b, h);

    for (int l = 0; l < NL; ++l) {
        qkv_part<<<dim3(8, 4, 12), 256, 0, stream>>>(h, Wq, Wk, Wv, qkvP, l);
        qkv_reduce<<<(420000 + 255) / 256, 256, 0, stream>>>(qkvP, bq, bk, bv, qkvAll, l);
        attn_split<<<dim3(8, HSC, 7), 256, 0, stream>>>(qkvAll, oPart, mPart, lPart);
        wo_combine<<<dim3(8, 4, 3), 256, 0, stream>>>(oPart, mPart, lPart,
                                                      Wo, bo, aAll, l);
        comb_part<<<dim3(8, 4, 12), 256, 0, stream>>>(
            aAll, Wc + (size_t)l * 3 * DD * DD, part);
        reduce_add_ln<<<NN, DD, 0, stream>>>(part, 12, bc + (size_t)l * DD, h,
                                             ln1_g + (size_t)l * DD, ln1_b + (size_t)l * DD);
        w1_part<<<dim3(32, 4, 4), 256, 0, stream>>>(
            h, W1 + (size_t)l * DD * FF, part);
        w1_reduce<<<(NN * FF + 255) / 256, 256, 0, stream>>>(
            part, b1 + (size_t)l * FF, f);
        w2_part<<<dim3(8, 4, 16), 256, 0, stream>>>(f, W2 + (size_t)l * FF * DD, part);
        reduce_add_ln<<<NN, DD, 0, stream>>>(part, 16, b2 + (size_t)l * DD, h,
                                             ln2_g + (size_t)l * DD, ln2_b + (size_t)l * DD);
    }
    col_mean_part<<<dim3(2, 25), 256, 0, stream>>>(h, headp);
    head_kernel<<<1, 256, 0, stream>>>(headp, head_W, head_b, out);
}

// Round 11
// 783.559 us; speedup vs baseline: 1.3064x; 1.1251x over previous
//
#include <hip/hip_runtime.h>
#include <math.h>

// Model constants: B=32, T=50000, P=100, D=512, H=16, L=6, C=256
// SCALES=[1,2,4], HS=5 heads/scale, KD=32, N=500 patches, FF=2048, EPS=1e-3.
//
// KEY INSIGHT (round 0, verified): first layernorm is over a size-1 axis ->
// output == ln_in_b[0] everywhere. h is batch-independent; network runs once
// on (500 x 512); final row broadcast x32.
//
// Ledger: R6 bf16-MFMA. R7/8 k-splits 999->839. R9 refused 1122. R10
// branch-free 965. R11 sched_barrier 864. R12 splits+branch-free 803.
// R13 deeper splits 797 (best). R14 attn-fusion 1024 (4x read amp).
// R15 wo_combine-only 881 -> wo_combine itself costs +84us vs separate
// attn_combine+wo_all (R9 inference was wrong). ALSO: attn_split now the
// biggest kernel: 42.5us x 6 = 255us, VALUBusy 7.9%, Occupancy 7.8% ->
// latency-bound at 210 valid blocks (~0.8/CU).
// Round 16 (this round): (a) revert to R13's attn_combine + wo_all;
// (b) attention key-split 128->64 (z=14: scale0 8sp, scale1 4sp, scale2
// 2sp) -> 420 valid blocks (~1.6/CU, ~6.5 waves/CU), per-block work
// halved; attn_combine widened to ns=8>>scale slices; oPart (8 slices)
// relocated into part region after dead qkvP.

#define DD 512
#define NN 500
#define HSC 5
#define KDD 32
#define QKVN 160
#define QKV3 480
#define FF 2048
#define NL 6
#define NC 256
#define NB 32
#define LNEPS 1e-3f
#define BM 128
#define BN 64
#define KCHB 64

// aAll sub-buffer offsets (floats)
#define AOFF1 256000
#define AOFF2 384000
// total attn rows over scales (500+250+125)
#define RTOT 875
#define OSZ 140000      // RTOT*160
#define MLSZ 4384       // RTOT*5 rounded up
#define QSP 420000      // qkv partial slice stride (floats)

typedef __attribute__((ext_vector_type(8))) short bf16x8;
typedef __attribute__((ext_vector_type(4))) float f32x4;

__device__ __forceinline__ float gelu_exact(float x) {
    return 0.5f * x * (1.0f + erff(x * 0.70710678118654752f));
}

// pack two f32 -> two bf16 (RNE) in one instr
__device__ __forceinline__ unsigned int pkbf(float a, float b) {
    unsigned int r;
    asm("v_cvt_pk_bf16_f32 %0, %1, %2" : "=v"(r) : "v"(a), "v"(b));
    return r;
}

// ======================= MFMA GEMM core =======================
// Tile: BM=128 x BN=64, 256 threads = 4 waves (2x2), K-chunk 64.
// A fp32 [M][K] (lda), POOL row-pooling or 3-scale GATHER (compile-time);
// B fp32 [K][N]: caller resolves per-thread column -> Bcol (always valid).
// ALL loads unconditional/branch-free: rows clamped to M-1 (dup rows never
// stored); TAIL>0: addresses clamped to klim, tail values masked via
// cndmask (A side only; B garbage x A-zero = 0).
// LDS row pitch 128B, swizzle byte ^= ((row&7)<<4) -> conflict-free b128.

template<int POOL, int GATHER, int TAIL>
__device__ __forceinline__ void mstage(
        const float* __restrict__ A, int lda,
        const float* __restrict__ Bcol, int ldb,
        int M, int bm, int k0, int klim,
        int ar4, int akq, int bkq,
        float4 (&aR)[2][4], float4 (&bR)[4]) {
    #pragma unroll
    for (int p = 0; p < 2; ++p) {
        int row = min(bm + ar4 + p * 64, M - 1);
        const float* ap;
        if (!GATHER) {
            ap = A + (size_t)row * POOL * lda;
        } else {
            int si = k0 >> 9;
            ap = A + (si == 0 ? 0 : (si == 1 ? AOFF1 : AOFF2))
               + (size_t)(row >> si) * DD - (size_t)(k0 & ~(DD - 1));
        }
        #pragma unroll
        for (int i = 0; i < 4; ++i) {
            int kk = akq + i * 4;
            int kg = TAIL ? min(k0 + kk, klim - 4) : (k0 + kk);
            float4 v = *(const float4*)(ap + kg);
            #pragma unroll
            for (int t = 1; t < POOL; ++t) {
                float4 u = *(const float4*)(ap + kg + (size_t)t * lda);
                v.x += u.x; v.y += u.y; v.z += u.z; v.w += u.w;
            }
            if (POOL > 1) {
                const float ip = 1.0f / (float)POOL;
                v.x *= ip; v.y *= ip; v.z *= ip; v.w *= ip;
            }
            if (TAIL) {
                bool ok = (k0 + kk) < klim;       // cndmask, no branch
                v.x = ok ? v.x : 0.f; v.y = ok ? v.y : 0.f;
                v.z = ok ? v.z : 0.f; v.w = ok ? v.w : 0.f;
            }
            aR[p][i] = v;
        }
    }
    #pragma unroll
    for (int i = 0; i < 4; ++i) {
        int kr = TAIL ? min(k0 + bkq + i, klim - 1) : (k0 + bkq + i);
        bR[i] = *(const float4*)(Bcol + (size_t)kr * ldb);
    }
}

template<int POOL, int GATHER, int TAIL>
__device__ __forceinline__ void mfma_core(
        const float* __restrict__ A, int lda,
        const float* __restrict__ Bcol, int ldb,
        int M, int bm, int ks, int nch, int klim, f32x4 (&acc)[4][2]) {
    __shared__ __align__(16) unsigned short As[128 * 64];   // 16 KB
    __shared__ __align__(16) unsigned short Bs[64 * 64];    // 8 KB
    const int tid = threadIdx.x;
    const int ar4 = tid >> 2, akq = (tid & 3) * 16;   // A: 2 rows, 16 k each
    const int bkq = (tid >> 4) * 4, bn4 = tid & 15;   // B: 4 k-rows, col quad
    const int lane = tid & 63, wid = tid >> 6;
    const int wm = wid >> 1, wn = wid & 1;

    float4 aR[2][4], bR[4];
    mstage<POOL, GATHER, TAIL>(A, lda, Bcol, ldb, M, bm, ks, klim,
                               ar4, akq, bkq, aR, bR);

    for (int c = 0; c < nch; ++c) {
        __syncthreads();
        // ---- regs -> LDS (cvt to bf16, swizzled) ----
        #pragma unroll
        for (int p = 0; p < 2; ++p) {
            int r = ar4 + p * 64;
            int swz = (r & 7) << 4;
            char* base = (char*)As + r * 128;
            #pragma unroll
            for (int i = 0; i < 4; ++i) {
                int cb = (akq + i * 4) * 2;
                *(uint2*)(base + (cb ^ swz)) = make_uint2(
                    pkbf(aR[p][i].x, aR[p][i].y), pkbf(aR[p][i].z, aR[p][i].w));
            }
        }
        {
            const float* b0 = (const float*)&bR[0];
            const float* b1 = (const float*)&bR[1];
            const float* b2 = (const float*)&bR[2];
            const float* b3 = (const float*)&bR[3];
            #pragma unroll
            for (int j = 0; j < 4; ++j) {
                int nrow = bn4 * 4 + j;
                char* base = (char*)Bs + nrow * 128;
                *(uint2*)(base + ((bkq * 2) ^ ((nrow & 7) << 4))) = make_uint2(
                    pkbf(b0[j], b1[j]), pkbf(b2[j], b3[j]));
            }
        }
        __syncthreads();
        if (c + 1 < nch)
            mstage<POOL, GATHER, TAIL>(A, lda, Bcol, ldb, M, bm,
                                       ks + (c + 1) * KCHB, klim,
                                       ar4, akq, bkq, aR, bR);
        // ---- compute: 2 k-steps of 32, 8 MFMA each per wave ----
        #pragma unroll
        for (int half = 0; half < 2; ++half) {
            const int kb = (half * 32 + (lane >> 4) * 8) * 2;
            bf16x8 af[4], bf[2];
            #pragma unroll
            for (int m = 0; m < 4; ++m) {
                int r = wm * 64 + m * 16 + (lane & 15);
                af[m] = *(const bf16x8*)((const char*)As + r * 128 + (kb ^ ((r & 7) << 4)));
            }
            #pragma unroll
            for (int n = 0; n < 2; ++n) {
                int r = wn * 32 + n * 16 + (lane & 15);
                bf[n] = *(const bf16x8*)((const char*)Bs + r * 128 + (kb ^ ((r & 7) << 4)));
            }
            #pragma unroll
            for (int m = 0; m < 4; ++m)
                #pragma unroll
                for (int n = 0; n < 2; ++n)
                    acc[m][n] = __builtin_amdgcn_mfma_f32_16x16x32_bf16(
                        af[m], bf[n], acc[m][n], 0, 0, 0);
        }
    }
}

#define MACC_INIT(acc) { _Pragma("unroll") for (int m_ = 0; m_ < 4; ++m_) \
    _Pragma("unroll") for (int n_ = 0; n_ < 2; ++n_) \
    _Pragma("unroll") for (int j_ = 0; j_ < 4; ++j_) acc[m_][n_][j_] = 0.f; }

// ======================= setup =======================
__global__ void colsum_kernel(const float* __restrict__ pw, float* __restrict__ csum) {
    int d = blockIdx.x * blockDim.x + threadIdx.x;
    if (d < DD) {
        float s = 0.f;
        for (int p = 0; p < 100; ++p) s += pw[p * DD + d];
        csum[d] = s;
    }
}

__global__ void init_h(const float* __restrict__ csum, const float* __restrict__ pb,
                       const float* __restrict__ pos, const float* __restrict__ lnb,
                       float* __restrict__ h) {
    int idx = blockIdx.x * 256 + threadIdx.x;
    if (idx >= NN * DD) return;
    int d = idx & (DD - 1);
    h[idx] = lnb[0] * csum[d] + pb[d] + pos[idx];
}

// ======================= QKV partial (all scales, k-split S=4) =============
__global__ __launch_bounds__(256, 2) void qkv_part(
        const float* __restrict__ h,
        const float* __restrict__ Wq, const float* __restrict__ Wk,
        const float* __restrict__ Wv,
        float* __restrict__ part, int l) {
    int scale = blockIdx.z >> 2, ps = blockIdx.z & 3;
    int n = NN >> scale;
    int bm = blockIdx.y * BM;
    if (bm >= n) return;
    int bn = blockIdx.x * BN;
    size_t w = (size_t)(l * 3 + scale);
    int tid = threadIdx.x;
    int col = min(bn + (tid & 15) * 4, QKV3 - 4);
    int which = (col >= 320) ? 2 : ((col >= 160) ? 1 : 0);
    const float* Wsel = (which == 0) ? Wq : ((which == 1) ? Wk : Wv);
    const float* Bcol = Wsel + w * DD * QKVN + (col - which * QKVN);
    float* outb = part + (size_t)ps * QSP
                + (scale == 0 ? 0 : (scale == 1 ? 240000 : 360000));

    f32x4 acc[4][2];
    MACC_INIT(acc);
    if (scale == 0)
        mfma_core<1, 0, 0>(h, DD, Bcol, QKVN, n, bm, ps * 128, 2, DD, acc);
    else if (scale == 1)
        mfma_core<2, 0, 0>(h, DD, Bcol, QKVN, n, bm, ps * 128, 2, DD, acc);
    else
        mfma_core<4, 0, 0>(h, DD, Bcol, QKVN, n, bm, ps * 128, 2, DD, acc);

    int lane = tid & 63, wid = tid >> 6, wm = wid >> 1, wn = wid & 1;
    #pragma unroll
    for (int q = 0; q < 2; ++q) {
        int cb = bn + wn * 32 + q * 16;
        if (cb >= QKV3) continue;
        int c2 = cb + (lane & 15);
        #pragma unroll
        for (int m = 0; m < 4; ++m) {
            int r0 = bm + wm * 64 + m * 16 + ((lane >> 4) << 2);
            #pragma unroll
            for (int j = 0; j < 4; ++j) {
                int r = r0 + j;
                if (r < n) outb[(size_t)r * QKV3 + c2] = acc[m][q][j];
            }
        }
    }
}

__global__ void qkv_reduce(const float* __restrict__ part,
                           const float* __restrict__ bq,
                           const float* __restrict__ bk,
                           const float* __restrict__ bv,
                           float* __restrict__ qkvAll, int l) {
    int idx = blockIdx.x * 256 + threadIdx.x;
    if (idx >= 420000) return;
    int scale, base;
    if (idx < 240000) { scale = 0; base = 0; }
    else if (idx < 360000) { scale = 1; base = 240000; }
    else { scale = 2; base = 360000; }
    int rowrem = (idx - base) % QKV3;
    int which = rowrem / QKVN;
    int col = rowrem - which * QKVN;
    float v = part[idx] + part[QSP + idx]
            + part[2 * QSP + idx] + part[3 * QSP + idx];
    v += ((which == 0) ? bq : (which == 1 ? bk : bv))[(size_t)(l * 3 + scale) * QKVN + col];
    qkvAll[idx] = v;
}

// ======================= attention: 64-key-split flash =====================
// grid (8, 5, 14): z -> (scale, sp): scale0 sp=z (8 x 64 keys);
// scale1 sp=z-8 (4); scale2 sp=z-12 (2). One 64-key chunk per block.
__global__ __launch_bounds__(256, 2) void attn_split(
        const float* __restrict__ qkvAll, float* __restrict__ oPart,
        float* __restrict__ mPart, float* __restrict__ lPart) {
    int z = blockIdx.z;
    int scale, sp;
    if (z < 8)       { scale = 0; sp = z; }
    else if (z < 12) { scale = 1; sp = z - 8; }
    else             { scale = 2; sp = z - 12; }
    int n = NN >> scale;
    int qt = blockIdx.x;
    if (qt * 64 >= n) return;
    int hh = blockIdx.y;
    int ks = sp * 64;
    int ke = min(n, ks + 64);
    const float* qkv = qkvAll + (scale == 0 ? 0 : (scale == 1 ? 240000 : 360000));
    int rowb = (scale == 0 ? 0 : (scale == 1 ? 500 : 750));

    int tid = threadIdx.x;
    int kg = tid & 7, qq = tid >> 3;
    int q0 = qt * 64 + qq, q1 = q0 + 32;
    bool ok0 = q0 < n, ok1 = q1 < n;

    float qa[32], qb[32];
    {
        const float* p0 = qkv + (size_t)(ok0 ? q0 : 0) * QKV3 + hh * KDD;
        const float* p1 = qkv + (size_t)(ok1 ? q1 : 0) * QKV3 + hh * KDD;
        #pragma unroll
        for (int c4 = 0; c4 < 8; ++c4) {
            float4 v0 = *(const float4*)(p0 + c4 * 4);
            float4 v1 = *(const float4*)(p1 + c4 * 4);
            qa[c4 * 4] = v0.x; qa[c4 * 4 + 1] = v0.y; qa[c4 * 4 + 2] = v0.z; qa[c4 * 4 + 3] = v0.w;
            qb[c4 * 4] = v1.x; qb[c4 * 4 + 1] = v1.y; qb[c4 * 4 + 2] = v1.z; qb[c4 * 4 + 3] = v1.w;
        }
    }

    __shared__ float Ks[64][36];
    __shared__ float Vs[64][36];
    float o0[32], o1[32];
    #pragma unroll
    for (int c = 0; c < 32; ++c) { o0[c] = 0.f; o1[c] = 0.f; }
    float m0 = -1e30f, m1 = -1e30f, l0 = 0.f, l1 = 0.f;

    int srow = tid >> 2, scol = tid & 3;

    {
        int kc = ks;
        int krow = kc + srow;
        bool ok = krow < ke;
        const float* kp = qkv + (size_t)(ok ? krow : 0) * QKV3 + QKVN + hh * KDD;
        #pragma unroll
        for (int half = 0; half < 2; ++half) {
            int cc = (half * 4 + scol) * 4;
            float4 kv = ok ? *(const float4*)(kp + cc) : make_float4(0.f, 0.f, 0.f, 0.f);
            float4 vv = ok ? *(const float4*)(kp + QKVN + cc) : make_float4(0.f, 0.f, 0.f, 0.f);
            Ks[srow][cc] = kv.x; Ks[srow][cc + 1] = kv.y; Ks[srow][cc + 2] = kv.z; Ks[srow][cc + 3] = kv.w;
            Vs[srow][cc] = vv.x; Vs[srow][cc + 1] = vv.y; Vs[srow][cc + 2] = vv.z; Vs[srow][cc + 3] = vv.w;
        }
        __syncthreads();

        float p0[8], p1[8];
        float cm = -1e30f;
        #pragma unroll
        for (int jj = 0; jj < 8; ++jj) {
            int j = jj * 8 + kg;
            float s0 = 0.f, s1 = 0.f;
            #pragma unroll
            for (int c4 = 0; c4 < 8; ++c4) {
                float4 kv = *(const float4*)&Ks[j][c4 * 4];
                s0 += qa[c4 * 4] * kv.x + qa[c4 * 4 + 1] * kv.y
                    + qa[c4 * 4 + 2] * kv.z + qa[c4 * 4 + 3] * kv.w;
                s1 += qb[c4 * 4] * kv.x + qb[c4 * 4 + 1] * kv.y
                    + qb[c4 * 4 + 2] * kv.z + qb[c4 * 4 + 3] * kv.w;
            }
            s0 *= 0.17677669529663687f;
            s1 *= 0.17677669529663687f;
            if (kc + j >= ke) { s0 = -1e30f; s1 = -1e30f; }
            p0[jj] = s0; p1[jj] = s1;
            cm = fmaxf(cm, fmaxf(s0, s1));
        }
        cm = fmaxf(cm, __shfl_xor(cm, 1));
        cm = fmaxf(cm, __shfl_xor(cm, 2));
        cm = fmaxf(cm, __shfl_xor(cm, 4));

        m0 = cm; m1 = cm;
        #pragma unroll
        for (int jj = 0; jj < 8; ++jj) {
            p0[jj] = expf(p0[jj] - cm); l0 += p0[jj];
            p1[jj] = expf(p1[jj] - cm); l1 += p1[jj];
        }
        #pragma unroll
        for (int jj = 0; jj < 8; ++jj) {
            int j = jj * 8 + kg;
            float w0 = p0[jj], w1 = p1[jj];
            #pragma unroll
            for (int c4 = 0; c4 < 8; ++c4) {
                float4 vv = *(const float4*)&Vs[j][c4 * 4];
                o0[c4 * 4]     += w0 * vv.x; o0[c4 * 4 + 1] += w0 * vv.y;
                o0[c4 * 4 + 2] += w0 * vv.z; o0[c4 * 4 + 3] += w0 * vv.w;
                o1[c4 * 4]     += w1 * vv.x; o1[c4 * 4 + 1] += w1 * vv.y;
                o1[c4 * 4 + 2] += w1 * vv.z; o1[c4 * 4 + 3] += w1 * vv.w;
            }
        }
    }
    #pragma unroll
    for (int st = 1; st < 8; st <<= 1) {
        l0 += __shfl_xor(l0, st);
        l1 += __shfl_xor(l1, st);
        #pragma unroll
        for (int c = 0; c < 32; ++c) {
            o0[c] += __shfl_xor(o0[c], st);
            o1[c] += __shfl_xor(o1[c], st);
        }
    }
    if (kg == 0) {
        float* ob = oPart + (size_t)sp * OSZ;
        if (ok0) {
            int r = rowb + q0;
            float* op = ob + (size_t)r * QKVN + hh * KDD;
            #pragma unroll
            for (int c4 = 0; c4 < 8; ++c4) {
                float4 v; v.x = o0[c4*4]; v.y = o0[c4*4+1]; v.z = o0[c4*4+2]; v.w = o0[c4*4+3];
                *(float4*)(op + c4 * 4) = v;
            }
            mPart[sp * MLSZ + r * HSC + hh] = m0;
            lPart[sp * MLSZ + r * HSC + hh] = l0;
        }
        if (ok1) {
            int r = rowb + q1;
            float* op = ob + (size_t)r * QKVN + hh * KDD;
            #pragma unroll
            for (int c4 = 0; c4 < 8; ++c4) {
                float4 v; v.x = o1[c4*4]; v.y = o1[c4*4+1]; v.z = o1[c4*4+2]; v.w = o1[c4*4+3];
                *(float4*)(op + c4 * 4) = v;
            }
            mPart[sp * MLSZ + r * HSC + hh] = m1;
            lPart[sp * MLSZ + r * HSC + hh] = l1;
        }
    }
}

// ns = 8 >> scale partial slices
__global__ void attn_combine(const float* __restrict__ oPart,
                             const float* __restrict__ mPart,
                             const float* __restrict__ lPart,
                             float* __restrict__ oAll) {
    int idx = blockIdx.x * 256 + threadIdx.x;
    if (idx >= OSZ) return;
    int rh = idx >> 5;
    int r = rh / HSC, hh = rh - r * HSC;
    int scale = (r < 500) ? 0 : (r < 750 ? 1 : 2);
    int ns = 8 >> scale;
    float M = -1e30f;
    for (int s = 0; s < ns; ++s) M = fmaxf(M, mPart[s * MLSZ + r * HSC + hh]);
    float L = 0.f, val = 0.f;
    for (int s = 0; s < ns; ++s) {
        float wgt = expf(mPart[s * MLSZ + r * HSC + hh] - M);
        L += wgt * lPart[s * MLSZ + r * HSC + hh];
        val += wgt * oPart[(size_t)s * OSZ + idx];
    }
    oAll[idx] = val / L;
}

// ======================= Wo (all scales, bias fused, TAIL=32) ==============
__global__ __launch_bounds__(256, 2) void wo_all(
        const float* __restrict__ oAll, const float* __restrict__ Wo,
        const float* __restrict__ bo, float* __restrict__ aAll, int l) {
    int z = blockIdx.z;
    int n = NN >> z;
    int bm = blockIdx.y * BM;
    if (bm >= n) return;
    int bn = blockIdx.x * BN;
    size_t w = (size_t)(l * 3 + z);
    const float* A = oAll + (z == 0 ? 0 : (z == 1 ? 80000 : 120000));
    float* C = aAll + (z == 0 ? 0 : (z == 1 ? AOFF1 : AOFF2));
    int tid = threadIdx.x;
    const float* Bcol = Wo + w * QKVN * DD + bn + (tid & 15) * 4;

    f32x4 acc[4][2];
    MACC_INIT(acc);
    // K=160: 3 chunks (64,64,32-masked), klim=160
    mfma_core<1, 0, 32>(A, QKVN, Bcol, DD, n, bm, 0, 3, QKVN, acc);

    const float* bias = bo + w * DD;
    int lane = tid & 63, wid = tid >> 6, wm = wid >> 1, wn = wid & 1;
    #pragma unroll
    for (int q = 0; q < 2; ++q) {
        int c2 = bn + wn * 32 + q * 16 + (lane & 15);
        float bv_ = bias[c2];
        #pragma unroll
        for (int m = 0; m < 4; ++m) {
            int r0 = bm + wm * 64 + m * 16 + ((lane >> 4) << 2);
            #pragma unroll
            for (int j = 0; j < 4; ++j) {
                int r = r0 + j;
                if (r < n) C[(size_t)r * DD + c2] = acc[m][q][j] + bv_;
            }
        }
    }
}

// ======================= comb partial (gather-A, k-split S=12) =============
__global__ __launch_bounds__(256, 2) void comb_part(
        const float* __restrict__ aAll, const float* __restrict__ Wc,
        float* __restrict__ part) {
    int zz = blockIdx.z;
    int bm = blockIdx.y * BM, bn = blockIdx.x * BN;
    int tid = threadIdx.x;
    const float* Bcol = Wc + bn + (tid & 15) * 4;
    f32x4 acc[4][2];
    MACC_INIT(acc);
    mfma_core<1, 1, 0>(aAll, DD, Bcol, DD, NN, bm, zz * 128, 2, 1536, acc);

    float* pz = part + (size_t)zz * NN * DD;
    int lane = tid & 63, wid = tid >> 6, wm = wid >> 1, wn = wid & 1;
    #pragma unroll
    for (int q = 0; q < 2; ++q) {
        int c2 = bn + wn * 32 + q * 16 + (lane & 15);
        #pragma unroll
        for (int m = 0; m < 4; ++m) {
            int r0 = bm + wm * 64 + m * 16 + ((lane >> 4) << 2);
            #pragma unroll
            for (int j = 0; j < 4; ++j) {
                int r = r0 + j;
                if (r < NN) pz[(size_t)r * DD + c2] = acc[m][q][j];
            }
        }
    }
}

// ======================= W1 partial (k-split S=4) ==========================
__global__ __launch_bounds__(256, 2) void w1_part(
        const float* __restrict__ h, const float* __restrict__ W1,
        float* __restrict__ part) {
    int sp = blockIdx.z;
    int bm = blockIdx.y * BM, bn = blockIdx.x * BN;
    int tid = threadIdx.x;
    const float* Bcol = W1 + bn + (tid & 15) * 4;
    f32x4 acc[4][2];
    MACC_INIT(acc);
    mfma_core<1, 0, 0>(h, DD, Bcol, FF, NN, bm, sp * 128, 2, DD, acc);

    float* pz = part + (size_t)sp * NN * FF;
    int lane = tid & 63, wid = tid >> 6, wm = wid >> 1, wn = wid & 1;
    #pragma unroll
    for (int q = 0; q < 2; ++q) {
        int c2 = bn + wn * 32 + q * 16 + (lane & 15);
        #pragma unroll
        for (int m = 0; m < 4; ++m) {
            int r0 = bm + wm * 64 + m * 16 + ((lane >> 4) << 2);
            #pragma unroll
            for (int j = 0; j < 4; ++j) {
                int r = r0 + j;
                if (r < NN) pz[(size_t)r * FF + c2] = acc[m][q][j];
            }
        }
    }
}

__global__ void w1_reduce(const float* __restrict__ part,
                          const float* __restrict__ b1, float* __restrict__ f) {
    int idx = blockIdx.x * 256 + threadIdx.x;
    if (idx >= NN * FF) return;
    float v = part[idx] + part[NN * FF + idx]
            + part[2 * NN * FF + idx] + part[3 * NN * FF + idx];
    f[idx] = gelu_exact(v + b1[idx & (FF - 1)]);
}

// ======================= W2 partial (k-split S=16) =========================
__global__ __launch_bounds__(256, 2) void w2_part(
        const float* __restrict__ f, const float* __restrict__ W2,
        float* __restrict__ part) {
    int sp = blockIdx.z;
    int bm = blockIdx.y * BM, bn = blockIdx.x * BN;
    int tid = threadIdx.x;
    const float* Bcol = W2 + bn + (tid & 15) * 4;
    f32x4 acc[4][2];
    MACC_INIT(acc);
    mfma_core<1, 0, 0>(f, FF, Bcol, DD, NN, bm, sp * 128, 2, FF, acc);

    float* pz = part + (size_t)sp * NN * DD;
    int lane = tid & 63, wid = tid >> 6, wm = wid >> 1, wn = wid & 1;
    #pragma unroll
    for (int q = 0; q < 2; ++q) {
        int c2 = bn + wn * 32 + q * 16 + (lane & 15);
        #pragma unroll
        for (int m = 0; m < 4; ++m) {
            int r0 = bm + wm * 64 + m * 16 + ((lane >> 4) << 2);
            #pragma unroll
            for (int j = 0; j < 4; ++j) {
                int r = r0 + j;
                if (r < NN) pz[(size_t)r * DD + c2] = acc[m][q][j];
            }
        }
    }
}

// ======================= fused reduce + bias + residual + LN ===============
__global__ void reduce_add_ln(const float* __restrict__ part, int S,
                              const float* __restrict__ bias,
                              float* __restrict__ h,
                              const float* __restrict__ gw,
                              const float* __restrict__ bw) {
    int row = blockIdx.x, t = threadIdx.x;
    size_t idx = (size_t)row * DD + t;
    float x = h[idx] + bias[t];
    for (int s = 0; s < S; ++s) x += part[(size_t)s * NN * DD + idx];
    int lane = t & 63, wv = t >> 6;
    __shared__ float s1[8], s2[8];
    __shared__ float mb[2];
    float sum = x, sq = x * x;
    for (int off = 32; off; off >>= 1) {
        sum += __shfl_down(sum, off);
        sq  += __shfl_down(sq,  off);
    }
    if (lane == 0) { s1[wv] = sum; s2[wv] = sq; }
    __syncthreads();
    if (t == 0) {
        float a = 0.f, b = 0.f;
        for (int i = 0; i < 8; ++i) { a += s1[i]; b += s2[i]; }
        float mean = a / (float)DD;
        float var = b / (float)DD - mean * mean;
        mb[0] = mean;
        mb[1] = rsqrtf(var + LNEPS);
    }
    __syncthreads();
    h[idx] = (x - mb[0]) * mb[1] * gw[t] + bw[t];
}

// ======================= head =======================
__global__ void col_mean_part(const float* __restrict__ h, float* __restrict__ partial) {
    int col = blockIdx.x * 256 + threadIdx.x;
    int r0 = blockIdx.y * 20;
    float s = 0.f;
    #pragma unroll
    for (int r = 0; r < 20; ++r) s += h[(size_t)(r0 + r) * DD + col];
    partial[(size_t)blockIdx.y * DD + col] = s;
}

__global__ void head_kernel(const float* __restrict__ partial,
                            const float* __restrict__ hw,
                            const float* __restrict__ hb, float* __restrict__ out) {
    __shared__ float gs[DD];
    __shared__ float r[4];
    __shared__ float bmx, bsum;
    int t = threadIdx.x;
    for (int d = t; d < DD; d += 256) {
        float s = 0.f;
        #pragma unroll
        for (int p = 0; p < 25; ++p) s += partial[(size_t)p * DD + d];
        gs[d] = s / (float)NN;
    }
    __syncthreads();
    float acc = hb[t];
    #pragma unroll 16
    for (int d = 0; d < DD; ++d) acc += gs[d] * hw[(size_t)d * NC + t];
    int lane = t & 63, wv = t >> 6;
    float mx = acc;
    for (int off = 32; off; off >>= 1) mx = fmaxf(mx, __shfl_down(mx, off));
    if (lane == 0) r[wv] = mx;
    __syncthreads();
    if (t == 0) bmx = fmaxf(fmaxf(r[0], r[1]), fmaxf(r[2], r[3]));
    __syncthreads();
    float e = expf(acc - bmx);
    float s = e;
    for (int off = 32; off; off >>= 1) s += __shfl_down(s, off);
    if (lane == 0) r[wv] = s;
    __syncthreads();
    if (t == 0) bsum = 1.f / (r[0] + r[1] + r[2] + r[3]);
    __syncthreads();
    float pv = e * bsum;
    for (int b = 0; b < NB; ++b) out[(size_t)b * NC + t] = pv;
}

extern "C" void kernel_launch(void* const* d_in, const int* in_sizes, int n_in,
                              void* d_out, int out_size, void* d_ws, size_t ws_size,
                              hipStream_t stream) {
    const float* ln_in_b = (const float*)d_in[2];
    const float* patch_W = (const float*)d_in[3];
    const float* patch_b = (const float*)d_in[4];
    const float* pos_emb = (const float*)d_in[5];
    const float* Wq = (const float*)d_in[6];
    const float* bq = (const float*)d_in[7];
    const float* Wk = (const float*)d_in[8];
    const float* bk = (const float*)d_in[9];
    const float* Wv = (const float*)d_in[10];
    const float* bv = (const float*)d_in[11];
    const float* Wo = (const float*)d_in[12];
    const float* bo = (const float*)d_in[13];
    const float* Wc = (const float*)d_in[14];
    const float* bc = (const float*)d_in[15];
    const float* ln1_g = (const float*)d_in[16];
    const float* ln1_b = (const float*)d_in[17];
    const float* W1 = (const float*)d_in[18];
    const float* b1 = (const float*)d_in[19];
    const float* W2 = (const float*)d_in[20];
    const float* b2 = (const float*)d_in[21];
    const float* ln2_g = (const float*)d_in[22];
    const float* ln2_b = (const float*)d_in[23];
    const float* head_W = (const float*)d_in[24];
    const float* head_b = (const float*)d_in[25];
    float* out = (float*)d_out;

    // workspace (floats). part region aliases: qkvP (dead after qkv_reduce),
    // then oPart/mPart/lPart (dead after attn_combine/wo), then comb/w1/w2
    // partials.
    float* ws = (float*)d_ws;
    float* h      = ws;                  // 256000
    float* csum   = h + 256000;          // 1024
    float* qkvAll = csum + 1024;         // 420000
    float* oAll   = qkvAll + 420000;     // 140000
    float* aAll   = oAll + 140000;       // 448000
    float* f      = aAll + 448000;       // 1024000
    float* part   = f + 1024000;         // 4194304
    float* headp  = part + 4194304;      // 12800
    float* qkvP   = part;                // 4*420000 = 1680000
    float* oPart  = part + 1680000;      // 8*140000 = 1120000
    float* mPart  = oPart + 1120000;     // 8*4384
    float* lPart  = mPart + 8 * MLSZ;    // 8*4384
    // (2870144 total < 4194304)

    colsum_kernel<<<1, 512, 0, stream>>>(patch_W, csum);
    init_h<<<(NN * DD + 255) / 256, 256, 0, stream>>>(csum, patch_b, pos_emb, ln_in_b, h);

    for (int l = 0; l < NL; ++l) {
        qkv_part<<<dim3(8, 4, 12), 256, 0, stream>>>(h, Wq, Wk, Wv, qkvP, l);
        qkv_reduce<<<(420000 + 255) / 256, 256, 0, stream>>>(qkvP, bq, bk, bv, qkvAll, l);
        attn_split<<<dim3(8, HSC, 14), 256, 0, stream>>>(qkvAll, oPart, mPart, lPart);
        attn_combine<<<(OSZ + 255) / 256, 256, 0, stream>>>(oPart, mPart, lPart, oAll);
        wo_all<<<dim3(8, 4, 3), 256, 0, stream>>>(oAll, Wo, bo, aAll, l);
        comb_part<<<dim3(8, 4, 12), 256, 0, stream>>>(
            aAll, Wc + (size_t)l * 3 * DD * DD, part);
        reduce_add_ln<<<NN, DD, 0, stream>>>(part, 12, bc + (size_t)l * DD, h,
                                             ln1_g + (size_t)l * DD, ln1_b + (size_t)l * DD);
        w1_part<<<dim3(32, 4, 4), 256, 0, stream>>>(
            h, W1 + (size_t)l * DD * FF, part);
        w1_reduce<<<(NN * FF + 255) / 256, 256, 0, stream>>>(
            part, b1 + (size_t)l * FF, f);
        w2_part<<<dim3(8, 4, 16), 256, 0, stream>>>(f, W2 + (size_t)l * FF * DD, part);
        reduce_add_ln<<<NN, DD, 0, stream>>>(part, 16, b2 + (size_t)l * DD, h,
                                             ln2_g + (size_t)l * DD, ln2_b + (size_t)l * DD);
    }
    col_mean_part<<<dim3(2, 25), 256, 0, stream>>>(h, headp);
    head_kernel<<<1, 256, 0, stream>>>(headp, head_W, head_b, out);
}